// Round 3
// baseline (530.639 us; speedup 1.0000x reference)
//
#include <hip/hip_runtime.h>

typedef __bf16 bf16;
typedef __attribute__((ext_vector_type(8))) __bf16 bf16x8;
typedef __attribute__((ext_vector_type(4))) float f32x4;

#define AS1 __attribute__((address_space(1)))
#define AS3 __attribute__((address_space(3)))

// tuple tables: combinations(range(8), 2), lexicographic
__device__ __constant__ int c_T0[28] = {0,0,0,0,0,0,0,1,1,1,1,1,1,2,2,2,2,2,3,3,3,3,4,4,4,5,5,6};
__device__ __constant__ int c_T1[28] = {1,2,3,4,5,6,7,2,3,4,5,6,7,3,4,5,6,7,4,5,6,7,5,6,7,6,7,7};

// ---------------------------------------------------------------------------
// X = [frames 4224 x 2048] bf16, frame f: queries f<4000, support 4000..4199,
// pad rows >=4200 zero.  Adds positional encoding PE[s][d].
__global__ __launch_bounds__(256) void fill_x(
    const float* __restrict__ queries, const float* __restrict__ support,
    bf16* __restrict__ X)
{
    const int f = blockIdx.x, tid = threadIdx.x;
    bf16* row = X + (long)f * 2048;
    const int d0 = tid << 3;
    if (f >= 4200) {
        bf16x8 z;
        #pragma unroll
        for (int i = 0; i < 8; ++i) z[i] = (bf16)0.f;
        *(bf16x8*)(row + d0) = z;
        return;
    }
    const float* src = (f < 4000) ? (queries + (long)f * 2048)
                                  : (support + (long)(f - 4000) * 2048);
    const int s = f & 7;
    bf16x8 o;
    #pragma unroll
    for (int i = 0; i < 8; ++i) {
        int d = d0 + i;
        float dv = __expf((float)(d >> 1) * -0.008994473019508f); // -ln(1e4)/1024
        float ang = (float)s * dv;
        float pe = (d & 1) ? __cosf(ang) : __sinf(ang);
        o[i] = (bf16)(src[d] + pe);
    }
    *(bf16x8*)(row + d0) = o;
}

// ---------------------------------------------------------------------------
// Wp [4608][2048] bf16 = transposed halves: n<1152: k_w[0:2048], 1152..: k_w[2048:],
// 2304..: v_w[0:2048], 3456..: v_w[2048:]
__global__ __launch_bounds__(256) void pack_w(
    const float* __restrict__ kw, const float* __restrict__ vw, bf16* __restrict__ Wp)
{
    __shared__ float t[32][33];
    const int k0 = blockIdx.x << 5, n0g = blockIdx.y << 5;
    const int tx = threadIdx.x & 31, ty = threadIdx.x >> 5;
    const int j = n0g / 1152, nc = n0g % 1152;
    const float* src = ((j < 2) ? kw : vw) + (long)(((j & 1) << 11) + k0) * 1152 + nc;
    #pragma unroll
    for (int i = 0; i < 4; ++i)
        t[ty + (i << 3)][tx] = src[(long)(ty + (i << 3)) * 1152 + tx];
    __syncthreads();
    #pragma unroll
    for (int i = 0; i < 4; ++i)
        Wp[(long)(n0g + ty + (i << 3)) * 2048 + k0 + tx] = (bf16)t[tx][ty + (i << 3)];
}

// ---------------------------------------------------------------------------
// C[M,N] = scale * A[M,K](bf16, leading dim lda) x B[N,K](bf16, ldb)^T
// Blocks with tile-row >= split_tm read from A2 (local row = m0 - split_tm*128).
// M,N multiples of 128; K multiple of 32.  128x128 tile, 4 waves 2x2,
// global_load_lds width=16, 16x16x32 bf16 MFMA.  OutT in {float, bf16}.
template <typename OutT>
__global__ __launch_bounds__(256) void gemm_bt(
    const bf16* __restrict__ A, const bf16* __restrict__ A2, int split_tm,
    long lda, const bf16* __restrict__ B, long ldb,
    OutT* __restrict__ C, int N, int K, float scale, int tiles_n)
{
    __shared__ __align__(16) bf16 lA[128 * 32];
    __shared__ __align__(16) bf16 lB[128 * 32];
    const int tid = threadIdx.x;
    const int wid = tid >> 6, lane = tid & 63;
    const int wm = (wid >> 1) << 6, wn = (wid & 1) << 6;
    const int quad = lane >> 4, l16 = lane & 15;
    const int tm = blockIdx.x / tiles_n, tn = blockIdx.x % tiles_n;
    const int m0 = tm << 7, n0 = tn << 7;
    const bf16* Abase = (tm < split_tm) ? (A + (long)m0 * lda)
                                        : (A2 + (long)(m0 - (split_tm << 7)) * lda);

    f32x4 acc[4][4];
    #pragma unroll
    for (int i = 0; i < 4; ++i)
        #pragma unroll
        for (int j = 0; j < 4; ++j)
            #pragma unroll
            for (int r = 0; r < 4; ++r) acc[i][j][r] = 0.f;

    const int srow = lane >> 2, scol = (lane & 3) << 3;
    for (int kk = 0; kk < K; kk += 32) {
        __syncthreads();
        #pragma unroll
        for (int p = 0; p < 2; ++p) {
            const int rbase = (wid << 5) + (p << 4);
            const bf16* ga = Abase + (long)(rbase + srow) * lda + kk + scol;
            const bf16* gb = B + (long)(n0 + rbase + srow) * ldb + kk + scol;
            __builtin_amdgcn_global_load_lds((const AS1 unsigned int*)ga,
                                             (AS3 unsigned int*)(lA + rbase * 32), 16, 0, 0);
            __builtin_amdgcn_global_load_lds((const AS1 unsigned int*)gb,
                                             (AS3 unsigned int*)(lB + rbase * 32), 16, 0, 0);
        }
        __builtin_amdgcn_s_waitcnt(0);
        __syncthreads();
        bf16x8 af[4], bfr[4];
        #pragma unroll
        for (int i = 0; i < 4; ++i)
            af[i] = *(const bf16x8*)(lA + (wm + (i << 4) + l16) * 32 + (quad << 3));
        #pragma unroll
        for (int j = 0; j < 4; ++j)
            bfr[j] = *(const bf16x8*)(lB + (wn + (j << 4) + l16) * 32 + (quad << 3));
        #pragma unroll
        for (int i = 0; i < 4; ++i)
            #pragma unroll
            for (int j = 0; j < 4; ++j)
                acc[i][j] = __builtin_amdgcn_mfma_f32_16x16x32_bf16(af[i], bfr[j], acc[i][j], 0, 0, 0);
    }
    #pragma unroll
    for (int i = 0; i < 4; ++i) {
        const int row = m0 + wm + (i << 4) + (quad << 2);
        #pragma unroll
        for (int j = 0; j < 4; ++j) {
            const int col = n0 + wn + (j << 4) + l16;
            OutT* cp = C + (long)row * N + col;
            #pragma unroll
            for (int r = 0; r < 4; ++r) cp[(long)r * N] = (OutT)(acc[i][j][r] * scale);
        }
    }
}

// ---------------------------------------------------------------------------
// One block per tuple-row: assemble K projections (LN) from bf16 half-proj H;
// V only for support rows.  Pad rows -> zeros.
// H[f][0:1152]=k_top, [1152:2304]=k_bot, [2304:3456]=v_top, [3456:4608]=v_bot.
__global__ __launch_bounds__(256) void proj_rows(
    const bf16* __restrict__ H, const float* __restrict__ kb,
    const float* __restrict__ vb, const float* __restrict__ gamma,
    const float* __restrict__ beta,
    bf16* __restrict__ qks, bf16* __restrict__ sks, bf16* __restrict__ svs)
{
    const int bid = blockIdx.x, tid = threadIdx.x;
    bf16 *outK, *outV = nullptr;
    int fi = 0, fj = 0;
    bool valid;
    if (bid < 14080) {
        outK = qks + (long)bid * 1152;
        valid = (bid < 14000);
        if (valid) {
            int q = bid / 28, t = bid - q * 28;
            fi = (q << 3) + c_T0[t];
            fj = (q << 3) + c_T1[t];
        }
    } else {
        int m2 = bid - 14080;
        outK = sks + (long)m2 * 1152;
        outV = svs + (long)m2 * 1152;
        valid = (m2 < 700);
        if (valid) {
            int n = m2 / 28, t = m2 - n * 28;
            fi = 4000 + (n << 3) + c_T0[t];
            fj = 4000 + (n << 3) + c_T1[t];
        }
    }
    if (!valid) {
        for (int d = tid; d < 1152; d += 256) {
            outK[d] = (bf16)0.f;
            if (outV) outV[d] = (bf16)0.f;
        }
        return;
    }
    const bf16* Hi = H + (long)fi * 4608;
    const bf16* Hj = H + (long)fj * 4608;
    float xv[5];
    float sum = 0.f, sumsq = 0.f;
    #pragma unroll
    for (int it = 0; it < 5; ++it) {
        int d = tid + (it << 8);
        float x = 0.f;
        if (d < 1152) {
            x = (float)Hi[d] + (float)Hj[1152 + d] + kb[d];
            sum += x; sumsq += x * x;
        }
        xv[it] = x;
    }
    #pragma unroll
    for (int off = 32; off > 0; off >>= 1) {
        sum += __shfl_xor(sum, off, 64);
        sumsq += __shfl_xor(sumsq, off, 64);
    }
    __shared__ float s1[4], s2[4];
    const int wid = tid >> 6;
    if ((tid & 63) == 0) { s1[wid] = sum; s2[wid] = sumsq; }
    __syncthreads();
    sum = s1[0] + s1[1] + s1[2] + s1[3];
    sumsq = s2[0] + s2[1] + s2[2] + s2[3];
    const float mu = sum * (1.f / 1152.f);
    const float var = sumsq * (1.f / 1152.f) - mu * mu;
    const float rs = rsqrtf(var + 1e-5f);
    #pragma unroll
    for (int it = 0; it < 5; ++it) {
        int d = tid + (it << 8);
        if (d < 1152) outK[d] = (bf16)((xv[it] - mu) * rs * gamma[d] + beta[d]);
    }
    if (outV) {
        #pragma unroll
        for (int it = 0; it < 5; ++it) {
            int d = tid + (it << 8);
            if (d < 1152) outV[d] = (bf16)((float)Hi[2304 + d] + (float)Hj[3456 + d] + vb[d]);
        }
    }
}

// ---------------------------------------------------------------------------
// Per query: QS[q] = sum_t ||Vt[fi] + Vb[fj] + vb||^2  via 61 dot products.
__global__ __launch_bounds__(256) void qs_pair(
    const bf16* __restrict__ H, const float* __restrict__ vb, float* __restrict__ QS)
{
    const int q = blockIdx.x;
    const int wid = threadIdx.x >> 6, lane = threadIdx.x & 63;
    __shared__ float dots[64];
    for (int task = wid; task <= 60; task += 4) {
        float s = 0.f;
        if (task == 60) {
            for (int d = lane; d < 1152; d += 64) { float v = vb[d]; s += v * v; }
        } else if (task < 8) {
            const bf16* p = H + (long)((q << 3) + task) * 4608 + 2304;
            for (int d = lane; d < 1152; d += 64) { float v = (float)p[d]; s += v * v; }
        } else if (task < 16) {
            const bf16* p = H + (long)((q << 3) + task - 8) * 4608 + 3456;
            for (int d = lane; d < 1152; d += 64) { float v = (float)p[d]; s += v * v; }
        } else if (task < 24) {
            const bf16* p = H + (long)((q << 3) + task - 16) * 4608 + 2304;
            for (int d = lane; d < 1152; d += 64) s += (float)p[d] * vb[d];
        } else if (task < 32) {
            const bf16* p = H + (long)((q << 3) + task - 24) * 4608 + 3456;
            for (int d = lane; d < 1152; d += 64) s += (float)p[d] * vb[d];
        } else {
            int t = task - 32;
            const bf16* pa = H + (long)((q << 3) + c_T0[t]) * 4608 + 2304;
            const bf16* pb = H + (long)((q << 3) + c_T1[t]) * 4608 + 3456;
            for (int d = lane; d < 1152; d += 64) s += (float)pa[d] * (float)pb[d];
        }
        #pragma unroll
        for (int off = 32; off > 0; off >>= 1) s += __shfl_xor(s, off, 64);
        if (lane == 0) dots[task] = s;
    }
    __syncthreads();
    if (threadIdx.x < 64) {
        float term = 0.f;
        if (lane < 28) {
            int i = c_T0[lane], j = c_T1[lane];
            term = dots[i] + dots[8 + j] + dots[60]
                 + 2.f * (dots[32 + lane] + dots[16 + i] + dots[24 + j]);
        }
        #pragma unroll
        for (int off = 32; off > 0; off >>= 1) term += __shfl_xor(term, off, 64);
        if (lane == 0) QS[q] = term;
    }
}

// ---------------------------------------------------------------------------
// bdot[u] = vb . svs[u]
__global__ __launch_bounds__(256) void bdot_k(
    const float* __restrict__ vb, const bf16* __restrict__ svs, float* __restrict__ bdot)
{
    const int u = (blockIdx.x << 2) + (threadIdx.x >> 6), lane = threadIdx.x & 63;
    const bf16* p = svs + (long)u * 1152;
    float s = 0.f;
    for (int d = lane; d < 1152; d += 64) s += vb[d] * (float)p[d];
    #pragma unroll
    for (int off = 32; off > 0; off >>= 1) s += __shfl_xor(s, off, 64);
    if (lane == 0) bdot[u] = s;
}

// ---------------------------------------------------------------------------
// Gram mask: Gb[768][768] bf16 = block-diag(per-class 140x140) of Gf (f32).
__global__ __launch_bounds__(256) void mask_gram(
    const float* __restrict__ Gf, bf16* __restrict__ Gb)
{
    int i = blockIdx.x * 256 + threadIdx.x; // 2304 blocks
    int r = i / 768, col = i - r * 768;
    bool keep = (r < 700) && (col < 700) && (r / 140 == col / 140);
    Gb[i] = keep ? (bf16)Gf[i] : (bf16)0.f;
}

// ---------------------------------------------------------------------------
// Per query-tuple row: 5 independent softmaxes over 140 (one wave each).
// Also zeroes the tail cols 700..767 (read by the attnG GEMM).
__global__ __launch_bounds__(320) void softmax_attn(
    const float* __restrict__ scores, bf16* __restrict__ attn)
{
    const int m = blockIdx.x, tid = threadIdx.x;
    bf16* arow = attn + (long)m * 768;
    if (m >= 14000) {
        for (int d = tid; d < 768; d += 320) arow[d] = (bf16)0.f;
        return;
    }
    if (tid < 68) arow[700 + tid] = (bf16)0.f;
    const int w = tid >> 6, lane = tid & 63;
    const float* srow = scores + (long)m * 768 + w * 140;
    float v0 = srow[lane];
    float v1 = srow[64 + lane];
    float v2 = (lane < 12) ? srow[128 + lane] : -1e30f;
    float mx = fmaxf(fmaxf(v0, v1), v2);
    #pragma unroll
    for (int off = 32; off > 0; off >>= 1) mx = fmaxf(mx, __shfl_xor(mx, off, 64));
    float e0 = __expf(v0 - mx), e1 = __expf(v1 - mx);
    float e2 = (lane < 12) ? __expf(v2 - mx) : 0.f;
    float s = e0 + e1 + e2;
    #pragma unroll
    for (int off = 32; off > 0; off >>= 1) s += __shfl_xor(s, off, 64);
    const float inv = 1.f / s;
    bf16* aw = arow + w * 140;
    aw[lane] = (bf16)(e0 * inv);
    aw[64 + lane] = (bf16)(e1 * inv);
    if (lane < 12) aw[128 + lane] = (bf16)(e2 * inv);
}

// ---------------------------------------------------------------------------
// dist[c][q] += sum_u a*(attnG - 2W),  W[m,u] = Fvt[fi,u] + Fvb[fj,u] + bdot[u].
// One wave per row m; grid = 14000/4.
__global__ __launch_bounds__(256) void final_dist(
    const bf16* __restrict__ attn, const bf16* __restrict__ attnG,
    const float* __restrict__ Fv, const float* __restrict__ bdot,
    float* __restrict__ dist)
{
    const int w = threadIdx.x >> 6, lane = threadIdx.x & 63;
    const int m = blockIdx.x * 4 + w; // < 14000
    const int q = m / 28, t = m - q * 28;
    const int fi = (q << 3) + c_T0[t], fj = (q << 3) + c_T1[t];
    const bf16* ar = attn + (long)m * 768;
    const bf16* gr = attnG + (long)m * 768;
    const float* ft = Fv + (long)fi * 768;
    const float* fb = Fv + (long)(4224 + fj) * 768;
    #pragma unroll
    for (int c = 0; c < 5; ++c) {
        const int base = c * 140;
        float s = 0.f;
        {
            int u = base + lane;
            float wv = ft[u] + fb[u] + bdot[u];
            s += (float)ar[u] * ((float)gr[u] - 2.f * wv);
        }
        {
            int u = base + 64 + lane;
            float wv = ft[u] + fb[u] + bdot[u];
            s += (float)ar[u] * ((float)gr[u] - 2.f * wv);
        }
        if (lane < 12) {
            int u = base + 128 + lane;
            float wv = ft[u] + fb[u] + bdot[u];
            s += (float)ar[u] * ((float)gr[u] - 2.f * wv);
        }
        #pragma unroll
        for (int off = 32; off > 0; off >>= 1) s += __shfl_xor(s, off, 64);
        if (lane == 0) atomicAdd(&dist[c * 500 + q], s);
    }
}

// ---------------------------------------------------------------------------
__global__ void finalize(const float* __restrict__ dist, const float* __restrict__ QS,
                         const float* __restrict__ gt, const float* __restrict__ tw,
                         float* __restrict__ out)
{
    int i = blockIdx.x * 256 + threadIdx.x;
    if (i < 2500) {
        int q = i / 5, c = i - q * 5;
        out[i] = -(dist[c * 500 + q] + QS[q]) * (gt[0] * tw[0] * (1.f / 28.f));
    }
}

// ---------------------------------------------------------------------------
extern "C" void kernel_launch(void* const* d_in, const int* in_sizes, int n_in,
                              void* d_out, int out_size, void* d_ws, size_t ws_size,
                              hipStream_t stream)
{
    const float* support = (const float*)d_in[0];
    const float* queries = (const float*)d_in[2];
    const float* kw      = (const float*)d_in[3];
    const float* kb      = (const float*)d_in[4];
    const float* vw      = (const float*)d_in[5];
    const float* vb      = (const float*)d_in[6];
    const float* gamma   = (const float*)d_in[7];
    const float* beta    = (const float*)d_in[8];
    const float* gt      = (const float*)d_in[9];
    const float* tw      = (const float*)d_in[10];
    float* out = (float*)d_out;

    const int BIG = 1 << 20; // split_tm sentinel: never split

    char* ws = (char*)d_ws;
    size_t off = 0;
    auto alloc = [&](size_t b) { char* p = ws + off; off += (b + 255) & ~(size_t)255; return p; };
    bf16* X      = (bf16*)alloc(4224ull * 2048 * 2);
    bf16* Wp     = (bf16*)alloc(4608ull * 2048 * 2);
    // union: H (bf16, 38.9 MB) lives first; scores (f32, 43.3 MB) overwrites it later
    char* uni    = alloc(14080ull * 768 * 4);
    bf16* H      = (bf16*)uni;                  // [4224 x 4608] bf16
    float* scores= (float*)uni;                 // [14080 x 768] f32 (after H is dead)
    bf16* qks    = (bf16*)alloc(14080ull * 1152 * 2);
    bf16* attnG  = (bf16*)qks;                  // [14080 x 768] bf16 (after qks dead)
    bf16* sks    = (bf16*)alloc(768ull * 1152 * 2);
    bf16* svs    = (bf16*)alloc(768ull * 1152 * 2);
    bf16* attn   = (bf16*)alloc(14080ull * 768 * 2);
    float* Fv    = (float*)alloc(8448ull * 768 * 4);
    float* Gf    = (float*)alloc(768ull * 768 * 4);
    bf16* Gb     = (bf16*)alloc(768ull * 768 * 2);
    float* bdot  = (float*)alloc(768 * 4);
    float* QS    = (float*)alloc(500 * 4);
    float* dist  = (float*)alloc(5 * 500 * 4);

    hipMemsetAsync(dist, 0, 5 * 500 * 4, stream);
    fill_x<<<4224, 256, 0, stream>>>(queries, support, X);
    pack_w<<<dim3(64, 144), 256, 0, stream>>>(kw, vw, Wp);
    // H[4224][4608] = X x Wp^T  (bf16 out)
    gemm_bt<bf16><<<33 * 36, 256, 0, stream>>>(X, X, BIG, 2048, Wp, 2048, H, 4608, 2048, 1.f, 36);
    proj_rows<<<14848, 256, 0, stream>>>(H, kb, vb, gamma, beta, qks, sks, svs);
    qs_pair<<<500, 256, 0, stream>>>(H, vb, QS);
    // Fv[8448][768] = [Vt; Vb] x svs^T  (A strided in H, split at tile-row 33)
    gemm_bt<float><<<66 * 6, 256, 0, stream>>>(H + 2304, H + 3456, 33, 4608, svs, 1152, Fv, 768, 1152, 1.f, 6);
    bdot_k<<<192, 256, 0, stream>>>(vb, svs, bdot);
    // Gram: Gf = svs x svs^T, then mask to block-diagonal bf16
    gemm_bt<float><<<6 * 6, 256, 0, stream>>>(svs, svs, BIG, 1152, svs, 1152, Gf, 768, 1152, 1.f, 6);
    mask_gram<<<2304, 256, 0, stream>>>(Gf, Gb);
    // scores[14080][768] = qks x sks^T / sqrt(1152)   (overwrites H region)
    gemm_bt<float><<<110 * 6, 256, 0, stream>>>(qks, qks, BIG, 1152, sks, 1152, scores, 768, 1152, 0.029462782549439484f, 6);
    softmax_attn<<<14080, 320, 0, stream>>>(scores, attn);
    // attnG[14080][768] = attn x Gb^T  (overwrites qks region)
    gemm_bt<bf16><<<110 * 6, 256, 0, stream>>>(attn, attn, BIG, 768, Gb, 768, attnG, 768, 768, 1.f, 6);
    final_dist<<<3500, 256, 0, stream>>>(attn, attnG, Fv, bdot, dist);
    finalize<<<10, 256, 0, stream>>>(dist, QS, gt, tw, out);
}

// Round 4
// 458.499 us; speedup vs baseline: 1.1573x; 1.1573x over previous
//
#include <hip/hip_runtime.h>

typedef __bf16 bf16;
typedef __attribute__((ext_vector_type(8))) __bf16 bf16x8;
typedef __attribute__((ext_vector_type(4))) float f32x4;

#define AS1 __attribute__((address_space(1)))
#define AS3 __attribute__((address_space(3)))

// tuple tables: combinations(range(8), 2), lexicographic
__device__ __constant__ int c_T0[28] = {0,0,0,0,0,0,0,1,1,1,1,1,1,2,2,2,2,2,3,3,3,3,4,4,4,5,5,6};
__device__ __constant__ int c_T1[28] = {1,2,3,4,5,6,7,2,3,4,5,6,7,3,4,5,6,7,4,5,6,7,5,6,7,6,7,7};

// ---------------------------------------------------------------------------
// Merged: blocks < 4224 fill X (frames + PE); blocks >= 4224 pack Wp.
// X = [4224 x 2048] bf16 (pad rows >= 4200 zero).
// Wp [4608][2048] bf16 = transposed halves of k_w / v_w.
__global__ __launch_bounds__(256) void fill_pack(
    const float* __restrict__ queries, const float* __restrict__ support,
    const float* __restrict__ kw, const float* __restrict__ vw,
    bf16* __restrict__ X, bf16* __restrict__ Wp)
{
    __shared__ float t[32][33];
    const int tid = threadIdx.x;
    if (blockIdx.x < 4224) {
        const int f = blockIdx.x;
        bf16* row = X + (long)f * 2048;
        const int d0 = tid << 3;
        if (f >= 4200) {
            bf16x8 z;
            #pragma unroll
            for (int i = 0; i < 8; ++i) z[i] = (bf16)0.f;
            *(bf16x8*)(row + d0) = z;
            return;
        }
        const float* src = (f < 4000) ? (queries + (long)f * 2048)
                                      : (support + (long)(f - 4000) * 2048);
        const int s = f & 7;
        bf16x8 o;
        #pragma unroll
        for (int i = 0; i < 8; ++i) {
            int d = d0 + i;
            float dv = __expf((float)(d >> 1) * -0.008994473019508f); // -ln(1e4)/1024
            float ang = (float)s * dv;
            float pe = (d & 1) ? __cosf(ang) : __sinf(ang);
            o[i] = (bf16)(src[d] + pe);
        }
        *(bf16x8*)(row + d0) = o;
    } else {
        const int b = blockIdx.x - 4224;
        const int k0 = (b & 63) << 5, n0g = (b >> 6) << 5;
        const int tx = tid & 31, ty = tid >> 5;
        const int j = n0g / 1152, nc = n0g % 1152;
        const float* src = ((j < 2) ? kw : vw) + (long)(((j & 1) << 11) + k0) * 1152 + nc;
        #pragma unroll
        for (int i = 0; i < 4; ++i)
            t[ty + (i << 3)][tx] = src[(long)(ty + (i << 3)) * 1152 + tx];
        __syncthreads();
        #pragma unroll
        for (int i = 0; i < 4; ++i)
            Wp[(long)(n0g + ty + (i << 3)) * 2048 + k0 + tx] = (bf16)t[tx][ty + (i << 3)];
    }
}

// ---------------------------------------------------------------------------
// C[M,N] = scale * A[M,K](bf16) x B[N,K](bf16, ldb)^T
// 3-way A segmentation by tile-row: tm < split1 -> A (lda), tm < split2 -> A2 (lda),
// else A3 (lda3).  CUTLASS-style GROUP_M=8 supertile swizzle for L2 locality.
// M,N multiples of 128; K multiple of 32.  128x128 tile, 4 waves 2x2,
// global_load_lds width=16, 16x16x32 bf16 MFMA.  OutT in {float, bf16}.
template <typename OutT>
__global__ __launch_bounds__(256) void gemm_bt(
    const bf16* __restrict__ A, const bf16* __restrict__ A2,
    const bf16* __restrict__ A3, int split1, int split2,
    long lda, long lda3, const bf16* __restrict__ B, long ldb,
    OutT* __restrict__ C, int N, int K, float scale, int tiles_n)
{
    __shared__ __align__(16) bf16 lA[128 * 32];
    __shared__ __align__(16) bf16 lB[128 * 32];
    const int tid = threadIdx.x;
    const int wid = tid >> 6, lane = tid & 63;
    const int wm = (wid >> 1) << 6, wn = (wid & 1) << 6;
    const int quad = lane >> 4, l16 = lane & 15;
    // supertile swizzle
    const int nbm = gridDim.x / tiles_n;
    const int grp = 8 * tiles_n;
    const int gid = blockIdx.x / grp;
    const int first = gid << 3;
    const int gsz = min(8, nbm - first);
    const int pig = blockIdx.x % grp;
    const int tm = first + (pig % gsz);
    const int tn = pig / gsz;
    const int m0 = tm << 7, n0 = tn << 7;
    long la = lda;
    const bf16* Abase;
    if (tm < split1)       Abase = A  + (long)m0 * lda;
    else if (tm < split2)  Abase = A2 + (long)(m0 - (split1 << 7)) * lda;
    else                 { Abase = A3 + (long)(m0 - (split2 << 7)) * lda3; la = lda3; }

    f32x4 acc[4][4];
    #pragma unroll
    for (int i = 0; i < 4; ++i)
        #pragma unroll
        for (int j = 0; j < 4; ++j)
            #pragma unroll
            for (int r = 0; r < 4; ++r) acc[i][j][r] = 0.f;

    const int srow = lane >> 2, scol = (lane & 3) << 3;
    for (int kk = 0; kk < K; kk += 32) {
        __syncthreads();
        #pragma unroll
        for (int p = 0; p < 2; ++p) {
            const int rbase = (wid << 5) + (p << 4);
            const bf16* ga = Abase + (long)(rbase + srow) * la + kk + scol;
            const bf16* gb = B + (long)(n0 + rbase + srow) * ldb + kk + scol;
            __builtin_amdgcn_global_load_lds((const AS1 unsigned int*)ga,
                                             (AS3 unsigned int*)(lA + rbase * 32), 16, 0, 0);
            __builtin_amdgcn_global_load_lds((const AS1 unsigned int*)gb,
                                             (AS3 unsigned int*)(lB + rbase * 32), 16, 0, 0);
        }
        __builtin_amdgcn_s_waitcnt(0);
        __syncthreads();
        bf16x8 af[4], bfr[4];
        #pragma unroll
        for (int i = 0; i < 4; ++i)
            af[i] = *(const bf16x8*)(lA + (wm + (i << 4) + l16) * 32 + (quad << 3));
        #pragma unroll
        for (int j = 0; j < 4; ++j)
            bfr[j] = *(const bf16x8*)(lB + (wn + (j << 4) + l16) * 32 + (quad << 3));
        #pragma unroll
        for (int i = 0; i < 4; ++i)
            #pragma unroll
            for (int j = 0; j < 4; ++j)
                acc[i][j] = __builtin_amdgcn_mfma_f32_16x16x32_bf16(af[i], bfr[j], acc[i][j], 0, 0, 0);
    }
    #pragma unroll
    for (int i = 0; i < 4; ++i) {
        const int row = m0 + wm + (i << 4) + (quad << 2);
        #pragma unroll
        for (int j = 0; j < 4; ++j) {
            const int col = n0 + wn + (j << 4) + l16;
            OutT* cp = C + (long)row * N + col;
            #pragma unroll
            for (int r = 0; r < 4; ++r) cp[(long)r * N] = (OutT)(acc[i][j][r] * scale);
        }
    }
}

// ---------------------------------------------------------------------------
// One block per tuple-row: assemble K projections (LN) from bf16 half-proj H;
// V only for support rows.  Pad rows -> zeros.
// H[f][0:1152]=k_top, [1152:2304]=k_bot, [2304:3456]=v_top, [3456:4608]=v_bot.
__global__ __launch_bounds__(256) void proj_rows(
    const bf16* __restrict__ H, const float* __restrict__ kb,
    const float* __restrict__ vb, const float* __restrict__ gamma,
    const float* __restrict__ beta,
    bf16* __restrict__ qks, bf16* __restrict__ sks, bf16* __restrict__ svs)
{
    const int bid = blockIdx.x, tid = threadIdx.x;
    bf16 *outK, *outV = nullptr;
    int fi = 0, fj = 0;
    bool valid;
    if (bid < 14080) {
        outK = qks + (long)bid * 1152;
        valid = (bid < 14000);
        if (valid) {
            int q = bid / 28, t = bid - q * 28;
            fi = (q << 3) + c_T0[t];
            fj = (q << 3) + c_T1[t];
        }
    } else {
        int m2 = bid - 14080;
        outK = sks + (long)m2 * 1152;
        outV = svs + (long)m2 * 1152;
        valid = (m2 < 700);
        if (valid) {
            int n = m2 / 28, t = m2 - n * 28;
            fi = 4000 + (n << 3) + c_T0[t];
            fj = 4000 + (n << 3) + c_T1[t];
        }
    }
    if (!valid) {
        for (int d = tid; d < 1152; d += 256) {
            outK[d] = (bf16)0.f;
            if (outV) outV[d] = (bf16)0.f;
        }
        return;
    }
    const bf16* Hi = H + (long)fi * 4608;
    const bf16* Hj = H + (long)fj * 4608;
    float xv[5];
    float sum = 0.f, sumsq = 0.f;
    #pragma unroll
    for (int it = 0; it < 5; ++it) {
        int d = tid + (it << 8);
        float x = 0.f;
        if (d < 1152) {
            x = (float)Hi[d] + (float)Hj[1152 + d] + kb[d];
            sum += x; sumsq += x * x;
        }
        xv[it] = x;
    }
    #pragma unroll
    for (int off = 32; off > 0; off >>= 1) {
        sum += __shfl_xor(sum, off, 64);
        sumsq += __shfl_xor(sumsq, off, 64);
    }
    __shared__ float s1[4], s2[4];
    const int wid = tid >> 6;
    if ((tid & 63) == 0) { s1[wid] = sum; s2[wid] = sumsq; }
    __syncthreads();
    sum = s1[0] + s1[1] + s1[2] + s1[3];
    sumsq = s2[0] + s2[1] + s2[2] + s2[3];
    const float mu = sum * (1.f / 1152.f);
    const float var = sumsq * (1.f / 1152.f) - mu * mu;
    const float rs = rsqrtf(var + 1e-5f);
    #pragma unroll
    for (int it = 0; it < 5; ++it) {
        int d = tid + (it << 8);
        if (d < 1152) outK[d] = (bf16)((xv[it] - mu) * rs * gamma[d] + beta[d]);
    }
    if (outV) {
        #pragma unroll
        for (int it = 0; it < 5; ++it) {
            int d = tid + (it << 8);
            if (d < 1152) outV[d] = (bf16)((float)Hi[2304 + d] + (float)Hj[3456 + d] + vb[d]);
        }
    }
}

// ---------------------------------------------------------------------------
// Per query: QS[q] = sum_t ||Vt[fi] + Vb[fj] + vb||^2 via 61 dots from LDS.
__global__ __launch_bounds__(256) void qs_pair(
    const bf16* __restrict__ H, const float* __restrict__ vb, float* __restrict__ QS)
{
    const int q = blockIdx.x, tid = threadIdx.x;
    __shared__ __align__(16) bf16 Vt[8 * 1152];
    __shared__ __align__(16) bf16 Vb[8 * 1152];
    __shared__ float dots[64];
    for (int idx = tid; idx < 1152; idx += 256) {
        int row = idx / 144, col = (idx - row * 144) << 3;
        const bf16* src = H + (long)((q << 3) + row) * 4608;
        *(bf16x8*)(Vt + row * 1152 + col) = *(const bf16x8*)(src + 2304 + col);
        *(bf16x8*)(Vb + row * 1152 + col) = *(const bf16x8*)(src + 3456 + col);
    }
    __syncthreads();
    const int wid = tid >> 6, lane = tid & 63;
    for (int task = wid; task <= 60; task += 4) {
        float s = 0.f;
        if (task == 60) {
            for (int c = lane << 3; c < 1152; c += 512) {
                #pragma unroll
                for (int k = 0; k < 8; ++k) { float v = vb[c + k]; s += v * v; }
            }
        } else if (task < 16) {
            const bf16* p = (task < 8) ? (Vt + task * 1152) : (Vb + (task - 8) * 1152);
            for (int c = lane << 3; c < 1152; c += 512) {
                bf16x8 v = *(const bf16x8*)(p + c);
                #pragma unroll
                for (int k = 0; k < 8; ++k) { float f = (float)v[k]; s += f * f; }
            }
        } else if (task < 32) {
            const bf16* p = (task < 24) ? (Vt + (task - 16) * 1152) : (Vb + (task - 24) * 1152);
            for (int c = lane << 3; c < 1152; c += 512) {
                bf16x8 v = *(const bf16x8*)(p + c);
                #pragma unroll
                for (int k = 0; k < 8; ++k) s += (float)v[k] * vb[c + k];
            }
        } else {
            int t = task - 32;
            const bf16* pa = Vt + c_T0[t] * 1152;
            const bf16* pb = Vb + c_T1[t] * 1152;
            for (int c = lane << 3; c < 1152; c += 512) {
                bf16x8 a = *(const bf16x8*)(pa + c);
                bf16x8 b = *(const bf16x8*)(pb + c);
                #pragma unroll
                for (int k = 0; k < 8; ++k) s += (float)a[k] * (float)b[k];
            }
        }
        #pragma unroll
        for (int off = 32; off > 0; off >>= 1) s += __shfl_xor(s, off, 64);
        if (lane == 0) dots[task] = s;
    }
    __syncthreads();
    if (tid < 64) {
        float term = 0.f;
        if (lane < 28) {
            int i = c_T0[lane], j = c_T1[lane];
            term = dots[i] + dots[8 + j] + dots[60]
                 + 2.f * (dots[32 + lane] + dots[16 + i] + dots[24 + j]);
        }
        #pragma unroll
        for (int off = 32; off > 0; off >>= 1) term += __shfl_xor(term, off, 64);
        if (lane == 0) QS[q] = term;
    }
}

// ---------------------------------------------------------------------------
// Merged small ops: blocks < 2304 mask Gram (block-diag, f32->bf16);
// blocks >= 2304 compute bdot[u] = vb . svs[u].
__global__ __launch_bounds__(256) void small_ops(
    const float* __restrict__ Gf, bf16* __restrict__ Gb,
    const float* __restrict__ vb, const bf16* __restrict__ svs,
    float* __restrict__ bdot)
{
    if (blockIdx.x < 2304) {
        int i = blockIdx.x * 256 + threadIdx.x;
        int r = i / 768, col = i - r * 768;
        bool keep = (r < 700) && (col < 700) && (r / 140 == col / 140);
        Gb[i] = keep ? (bf16)Gf[i] : (bf16)0.f;
    } else {
        const int u = ((blockIdx.x - 2304) << 2) + (threadIdx.x >> 6);
        const int lane = threadIdx.x & 63;
        const bf16* p = svs + (long)u * 1152;
        float s = 0.f;
        for (int d = lane; d < 1152; d += 64) s += vb[d] * (float)p[d];
        #pragma unroll
        for (int off = 32; off > 0; off >>= 1) s += __shfl_xor(s, off, 64);
        if (lane == 0) bdot[u] = s;
    }
}

// ---------------------------------------------------------------------------
// Per query-tuple row: 5 independent softmaxes over 140 (one wave each).
// Also zeroes the tail cols 700..767 (read by the attnG GEMM).
__global__ __launch_bounds__(320) void softmax_attn(
    const float* __restrict__ scores, bf16* __restrict__ attn)
{
    const int m = blockIdx.x, tid = threadIdx.x;
    bf16* arow = attn + (long)m * 768;
    if (m >= 14000) {
        for (int d = tid; d < 768; d += 320) arow[d] = (bf16)0.f;
        return;
    }
    if (tid < 68) arow[700 + tid] = (bf16)0.f;
    const int w = tid >> 6, lane = tid & 63;
    const float* srow = scores + (long)m * 768 + w * 140;
    float v0 = srow[lane];
    float v1 = srow[64 + lane];
    float v2 = (lane < 12) ? srow[128 + lane] : -1e30f;
    float mx = fmaxf(fmaxf(v0, v1), v2);
    #pragma unroll
    for (int off = 32; off > 0; off >>= 1) mx = fmaxf(mx, __shfl_xor(mx, off, 64));
    float e0 = __expf(v0 - mx), e1 = __expf(v1 - mx);
    float e2 = (lane < 12) ? __expf(v2 - mx) : 0.f;
    float s = e0 + e1 + e2;
    #pragma unroll
    for (int off = 32; off > 0; off >>= 1) s += __shfl_xor(s, off, 64);
    const float inv = 1.f / s;
    bf16* aw = arow + w * 140;
    aw[lane] = (bf16)(e0 * inv);
    aw[64 + lane] = (bf16)(e1 * inv);
    if (lane < 12) aw[128 + lane] = (bf16)(e2 * inv);
}

// ---------------------------------------------------------------------------
// dist[c][q] += sum_u a*(attnG - 2W),  W[m,u] = Fvt[fi,u] + Fvb[fj,u] + bdot[u].
// One wave per row m; grid = 14000/4.
__global__ __launch_bounds__(256) void final_dist(
    const bf16* __restrict__ attn, const bf16* __restrict__ attnG,
    const float* __restrict__ Fv, const float* __restrict__ bdot,
    float* __restrict__ dist)
{
    const int w = threadIdx.x >> 6, lane = threadIdx.x & 63;
    const int m = blockIdx.x * 4 + w; // < 14000
    const int q = m / 28, t = m - q * 28;
    const int fi = (q << 3) + c_T0[t], fj = (q << 3) + c_T1[t];
    const bf16* ar = attn + (long)m * 768;
    const bf16* gr = attnG + (long)m * 768;
    const float* ft = Fv + (long)fi * 768;
    const float* fb = Fv + (long)(4224 + fj) * 768;
    #pragma unroll
    for (int c = 0; c < 5; ++c) {
        const int base = c * 140;
        float s = 0.f;
        {
            int u = base + lane;
            float wv = ft[u] + fb[u] + bdot[u];
            s += (float)ar[u] * ((float)gr[u] - 2.f * wv);
        }
        {
            int u = base + 64 + lane;
            float wv = ft[u] + fb[u] + bdot[u];
            s += (float)ar[u] * ((float)gr[u] - 2.f * wv);
        }
        if (lane < 12) {
            int u = base + 128 + lane;
            float wv = ft[u] + fb[u] + bdot[u];
            s += (float)ar[u] * ((float)gr[u] - 2.f * wv);
        }
        #pragma unroll
        for (int off = 32; off > 0; off >>= 1) s += __shfl_xor(s, off, 64);
        if (lane == 0) atomicAdd(&dist[c * 500 + q], s);
    }
}

// ---------------------------------------------------------------------------
__global__ void finalize(const float* __restrict__ dist, const float* __restrict__ QS,
                         const float* __restrict__ gt, const float* __restrict__ tw,
                         float* __restrict__ out)
{
    int i = blockIdx.x * 256 + threadIdx.x;
    if (i < 2500) {
        int q = i / 5, c = i - q * 5;
        out[i] = -(dist[c * 500 + q] + QS[q]) * (gt[0] * tw[0] * (1.f / 28.f));
    }
}

// ---------------------------------------------------------------------------
extern "C" void kernel_launch(void* const* d_in, const int* in_sizes, int n_in,
                              void* d_out, int out_size, void* d_ws, size_t ws_size,
                              hipStream_t stream)
{
    const float* support = (const float*)d_in[0];
    const float* queries = (const float*)d_in[2];
    const float* kw      = (const float*)d_in[3];
    const float* kb      = (const float*)d_in[4];
    const float* vw      = (const float*)d_in[5];
    const float* vb      = (const float*)d_in[6];
    const float* gamma   = (const float*)d_in[7];
    const float* beta    = (const float*)d_in[8];
    const float* gt      = (const float*)d_in[9];
    const float* tw      = (const float*)d_in[10];
    float* out = (float*)d_out;

    const int BIG = 1 << 20; // split sentinel: never split

    char* ws = (char*)d_ws;
    size_t off = 0;
    auto alloc = [&](size_t b) { char* p = ws + off; off += (b + 255) & ~(size_t)255; return p; };
    bf16* X      = (bf16*)alloc(4224ull * 2048 * 2);
    bf16* Wp     = (bf16*)alloc(4608ull * 2048 * 2);
    // union: H (bf16, 38.9 MB) lives first; scores (f32, 43.3 MB) overwrites it later
    char* uni    = alloc(14080ull * 768 * 4);
    bf16* H      = (bf16*)uni;                  // [4224 x 4608] bf16
    float* scores= (float*)uni;                 // [14080 x 768] f32 (after H is dead)
    bf16* qks    = (bf16*)alloc(14080ull * 1152 * 2);
    bf16* attnG  = (bf16*)qks;                  // [14080 x 768] bf16 (after qks dead)
    bf16* sks    = (bf16*)alloc(768ull * 1152 * 2);
    bf16* svs    = (bf16*)alloc(768ull * 1152 * 2);
    bf16* attn   = (bf16*)alloc(14080ull * 768 * 2);
    float* Fv    = (float*)alloc(9216ull * 768 * 4);  // [Fvt(4224); Fvb(4224); Gf(768)]
    float* Gf    = Fv + 8448ull * 768;
    bf16* Gb     = (bf16*)alloc(768ull * 768 * 2);
    float* bdot  = (float*)alloc(768 * 4);
    float* QS    = (float*)alloc(500 * 4);
    float* dist  = (float*)alloc(5 * 500 * 4);

    hipMemsetAsync(dist, 0, 5 * 500 * 4, stream);
    fill_pack<<<4224 + 9216, 256, 0, stream>>>(queries, support, kw, vw, X, Wp);
    // H[4224][4608] = X x Wp^T  (bf16 out)
    gemm_bt<bf16><<<33 * 36, 256, 0, stream>>>(X, X, X, BIG, BIG, 2048, 2048, Wp, 2048,
                                               H, 4608, 2048, 1.f, 36);
    proj_rows<<<14848, 256, 0, stream>>>(H, kb, vb, gamma, beta, qks, sks, svs);
    qs_pair<<<500, 256, 0, stream>>>(H, vb, QS);
    // [Fvt; Fvb; Gf][9216][768] = [Vt(H-strided); Vb(H-strided); svs] x svs^T
    gemm_bt<float><<<72 * 6, 256, 0, stream>>>(H + 2304, H + 3456, svs, 33, 66, 4608, 1152,
                                               svs, 1152, Fv, 768, 1152, 1.f, 6);
    small_ops<<<2304 + 192, 256, 0, stream>>>(Gf, Gb, vb, svs, bdot);
    // scores[14080][768] = qks x sks^T / sqrt(1152)   (overwrites H region)
    gemm_bt<float><<<110 * 6, 256, 0, stream>>>(qks, qks, qks, BIG, BIG, 1152, 1152, sks, 1152,
                                                scores, 768, 1152, 0.029462782549439484f, 6);
    softmax_attn<<<14080, 320, 0, stream>>>(scores, attn);
    // attnG[14080][768] = attn x Gb^T  (overwrites qks region)
    gemm_bt<bf16><<<110 * 6, 256, 0, stream>>>(attn, attn, attn, BIG, BIG, 768, 768, Gb, 768,
                                               attnG, 768, 768, 1.f, 6);
    final_dist<<<3500, 256, 0, stream>>>(attn, attnG, Fv, bdot, dist);
    finalize<<<10, 256, 0, stream>>>(dist, QS, gt, tw, out);
}

// Round 5
// 423.521 us; speedup vs baseline: 1.2529x; 1.0826x over previous
//
#include <hip/hip_runtime.h>

typedef __bf16 bf16;
typedef __attribute__((ext_vector_type(8))) __bf16 bf16x8;
typedef __attribute__((ext_vector_type(4))) float f32x4;

#define AS1 __attribute__((address_space(1)))
#define AS3 __attribute__((address_space(3)))

// tuple tables: combinations(range(8), 2), lexicographic
__device__ __constant__ int c_T0[28] = {0,0,0,0,0,0,0,1,1,1,1,1,1,2,2,2,2,2,3,3,3,3,4,4,4,5,5,6};
__device__ __constant__ int c_T1[28] = {1,2,3,4,5,6,7,2,3,4,5,6,7,3,4,5,6,7,4,5,6,7,5,6,7,6,7,7};

// ---------------------------------------------------------------------------
// Merged: blocks < 4224 fill X (frames + PE); blocks >= 4224 pack Wp.
__global__ __launch_bounds__(256) void fill_pack(
    const float* __restrict__ queries, const float* __restrict__ support,
    const float* __restrict__ kw, const float* __restrict__ vw,
    bf16* __restrict__ X, bf16* __restrict__ Wp)
{
    __shared__ float t[32][33];
    const int tid = threadIdx.x;
    if (blockIdx.x < 4224) {
        const int f = blockIdx.x;
        bf16* row = X + (long)f * 2048;
        const int d0 = tid << 3;
        if (f >= 4200) {
            bf16x8 z;
            #pragma unroll
            for (int i = 0; i < 8; ++i) z[i] = (bf16)0.f;
            *(bf16x8*)(row + d0) = z;
            return;
        }
        const float* src = (f < 4000) ? (queries + (long)f * 2048)
                                      : (support + (long)(f - 4000) * 2048);
        const int s = f & 7;
        bf16x8 o;
        #pragma unroll
        for (int i = 0; i < 8; ++i) {
            int d = d0 + i;
            float dv = __expf((float)(d >> 1) * -0.008994473019508f); // -ln(1e4)/1024
            float ang = (float)s * dv;
            float pe = (d & 1) ? __cosf(ang) : __sinf(ang);
            o[i] = (bf16)(src[d] + pe);
        }
        *(bf16x8*)(row + d0) = o;
    } else {
        const int b = blockIdx.x - 4224;
        const int k0 = (b & 63) << 5, n0g = (b >> 6) << 5;
        const int tx = tid & 31, ty = tid >> 5;
        const int j = n0g / 1152, nc = n0g % 1152;
        const float* src = ((j < 2) ? kw : vw) + (long)(((j & 1) << 11) + k0) * 1152 + nc;
        #pragma unroll
        for (int i = 0; i < 4; ++i)
            t[ty + (i << 3)][tx] = src[(long)(ty + (i << 3)) * 1152 + tx];
        __syncthreads();
        #pragma unroll
        for (int i = 0; i < 4; ++i)
            Wp[(long)(n0g + ty + (i << 3)) * 2048 + k0 + tx] = (bf16)t[tx][ty + (i << 3)];
    }
}

// ---------------------------------------------------------------------------
// C[M,N] = scale * A[M,K](bf16, lda) x B[N,K](bf16, ldb)^T.  Simple row-major
// block order (no swizzle — R4 showed swizzle hurts locality here).
template <typename OutT>
__global__ __launch_bounds__(256) void gemm_bt(
    const bf16* __restrict__ A, long lda, const bf16* __restrict__ B, long ldb,
    OutT* __restrict__ C, int N, int K, float scale, int tiles_n)
{
    __shared__ __align__(16) bf16 lA[128 * 32];
    __shared__ __align__(16) bf16 lB[128 * 32];
    const int tid = threadIdx.x;
    const int wid = tid >> 6, lane = tid & 63;
    const int wm = (wid >> 1) << 6, wn = (wid & 1) << 6;
    const int quad = lane >> 4, l16 = lane & 15;
    const int tm = blockIdx.x / tiles_n, tn = blockIdx.x % tiles_n;
    const int m0 = tm << 7, n0 = tn << 7;
    const bf16* Abase = A + (long)m0 * lda;

    f32x4 acc[4][4];
    #pragma unroll
    for (int i = 0; i < 4; ++i)
        #pragma unroll
        for (int j = 0; j < 4; ++j)
            #pragma unroll
            for (int r = 0; r < 4; ++r) acc[i][j][r] = 0.f;

    const int srow = lane >> 2, scol = (lane & 3) << 3;
    for (int kk = 0; kk < K; kk += 32) {
        __syncthreads();
        #pragma unroll
        for (int p = 0; p < 2; ++p) {
            const int rbase = (wid << 5) + (p << 4);
            const bf16* ga = Abase + (long)(rbase + srow) * lda + kk + scol;
            const bf16* gb = B + (long)(n0 + rbase + srow) * ldb + kk + scol;
            __builtin_amdgcn_global_load_lds((const AS1 unsigned int*)ga,
                                             (AS3 unsigned int*)(lA + rbase * 32), 16, 0, 0);
            __builtin_amdgcn_global_load_lds((const AS1 unsigned int*)gb,
                                             (AS3 unsigned int*)(lB + rbase * 32), 16, 0, 0);
        }
        __builtin_amdgcn_s_waitcnt(0);
        __syncthreads();
        bf16x8 af[4], bfr[4];
        #pragma unroll
        for (int i = 0; i < 4; ++i)
            af[i] = *(const bf16x8*)(lA + (wm + (i << 4) + l16) * 32 + (quad << 3));
        #pragma unroll
        for (int j = 0; j < 4; ++j)
            bfr[j] = *(const bf16x8*)(lB + (wn + (j << 4) + l16) * 32 + (quad << 3));
        #pragma unroll
        for (int i = 0; i < 4; ++i)
            #pragma unroll
            for (int j = 0; j < 4; ++j)
                acc[i][j] = __builtin_amdgcn_mfma_f32_16x16x32_bf16(af[i], bfr[j], acc[i][j], 0, 0, 0);
    }
    #pragma unroll
    for (int i = 0; i < 4; ++i) {
        const int row = m0 + wm + (i << 4) + (quad << 2);
        #pragma unroll
        for (int j = 0; j < 4; ++j) {
            const int col = n0 + wn + (j << 4) + l16;
            OutT* cp = C + (long)row * N + col;
            #pragma unroll
            for (int r = 0; r < 4; ++r) cp[(long)r * N] = (OutT)(acc[i][j][r] * scale);
        }
    }
}

// ---------------------------------------------------------------------------
// Per-frame GEMMs in one launch.  828 blocks:
//   bid <  792: seg = bid/198 in {0:Fkt, 1:Fkb, 2:Fvt, 3:Fvb};
//               A = H col-segment seg*1152 (lda 4608), B = (seg<2 ? Bk : svs),
//               C = FG + seg*4224 rows (f32).
//   bid >= 792: Gram = svs x svs^T, block-diag masked, bf16 -> Gb.
__global__ __launch_bounds__(256) void gemm_frames(
    const bf16* __restrict__ H, const bf16* __restrict__ Bk,
    const bf16* __restrict__ svs, float* __restrict__ FG, bf16* __restrict__ Gb)
{
    __shared__ __align__(16) bf16 lA[128 * 32];
    __shared__ __align__(16) bf16 lB[128 * 32];
    const int tid = threadIdx.x;
    const int wid = tid >> 6, lane = tid & 63;
    const int wm = (wid >> 1) << 6, wn = (wid & 1) << 6;
    const int quad = lane >> 4, l16 = lane & 15;
    const bool gram = (int)blockIdx.x >= 792;
    int seg = 4, tm, tn;
    const bf16* Abase;
    long la;
    const bf16* B;
    if (!gram) {
        seg = blockIdx.x / 198;
        int r = blockIdx.x % 198;
        tm = r / 6; tn = r % 6;
        Abase = H + seg * 1152 + (long)(tm << 7) * 4608;
        la = 4608;
        B = (seg < 2) ? Bk : svs;
    } else {
        int r = blockIdx.x - 792;
        tm = r / 6; tn = r % 6;
        Abase = svs + (long)(tm << 7) * 1152;
        la = 1152;
        B = svs;
    }
    const int n0 = tn << 7;

    f32x4 acc[4][4];
    #pragma unroll
    for (int i = 0; i < 4; ++i)
        #pragma unroll
        for (int j = 0; j < 4; ++j)
            #pragma unroll
            for (int r = 0; r < 4; ++r) acc[i][j][r] = 0.f;

    const int srow = lane >> 2, scol = (lane & 3) << 3;
    for (int kk = 0; kk < 1152; kk += 32) {
        __syncthreads();
        #pragma unroll
        for (int p = 0; p < 2; ++p) {
            const int rbase = (wid << 5) + (p << 4);
            const bf16* ga = Abase + (long)(rbase + srow) * la + kk + scol;
            const bf16* gb = B + (long)(n0 + rbase + srow) * 1152 + kk + scol;
            __builtin_amdgcn_global_load_lds((const AS1 unsigned int*)ga,
                                             (AS3 unsigned int*)(lA + rbase * 32), 16, 0, 0);
            __builtin_amdgcn_global_load_lds((const AS1 unsigned int*)gb,
                                             (AS3 unsigned int*)(lB + rbase * 32), 16, 0, 0);
        }
        __builtin_amdgcn_s_waitcnt(0);
        __syncthreads();
        bf16x8 af[4], bfr[4];
        #pragma unroll
        for (int i = 0; i < 4; ++i)
            af[i] = *(const bf16x8*)(lA + (wm + (i << 4) + l16) * 32 + (quad << 3));
        #pragma unroll
        for (int j = 0; j < 4; ++j)
            bfr[j] = *(const bf16x8*)(lB + (wn + (j << 4) + l16) * 32 + (quad << 3));
        #pragma unroll
        for (int i = 0; i < 4; ++i)
            #pragma unroll
            for (int j = 0; j < 4; ++j)
                acc[i][j] = __builtin_amdgcn_mfma_f32_16x16x32_bf16(af[i], bfr[j], acc[i][j], 0, 0, 0);
    }
    #pragma unroll
    for (int i = 0; i < 4; ++i) {
        const int rloc = (tm << 7) + wm + (i << 4) + (quad << 2);
        #pragma unroll
        for (int j = 0; j < 4; ++j) {
            const int col = n0 + wn + (j << 4) + l16;
            #pragma unroll
            for (int r = 0; r < 4; ++r) {
                const int row = rloc + r;
                if (!gram) {
                    FG[(long)(seg * 4224 + row) * 768 + col] = acc[i][j][r];
                } else {
                    bool keep = (row < 700) && (col < 700) && (row / 140 == col / 140);
                    Gb[(long)row * 768 + col] = keep ? (bf16)acc[i][j][r] : (bf16)0.f;
                }
            }
        }
    }
}

// ---------------------------------------------------------------------------
// Support tuple rows only (768 blocks; valid < 700): K-LN -> Bk = gamma .* sks,
// V -> svs.  Per-row scalars: gd = sum(gamma*sks), kbd = sum(kb*gamma*sks),
// bd2 = sum(beta*sks), bdot = sum(vb*svs).
__global__ __launch_bounds__(256) void proj_support(
    const bf16* __restrict__ H, const float* __restrict__ kb,
    const float* __restrict__ vb, const float* __restrict__ gamma,
    const float* __restrict__ beta,
    bf16* __restrict__ Bk, bf16* __restrict__ svs,
    float* __restrict__ gd, float* __restrict__ kbd,
    float* __restrict__ bd2, float* __restrict__ bdot)
{
    const int u = blockIdx.x, tid = threadIdx.x;
    bf16* outK = Bk + (long)u * 1152;
    bf16* outV = svs + (long)u * 1152;
    if (u >= 700) {
        for (int d = tid; d < 1152; d += 256) { outK[d] = (bf16)0.f; outV[d] = (bf16)0.f; }
        if (tid == 0) { gd[u] = 0.f; kbd[u] = 0.f; bd2[u] = 0.f; bdot[u] = 0.f; }
        return;
    }
    const int n = u / 28, t = u - n * 28;
    const int fi = 4000 + (n << 3) + c_T0[t];
    const int fj = 4000 + (n << 3) + c_T1[t];
    const bf16* Hi = H + (long)fi * 4608;
    const bf16* Hj = H + (long)fj * 4608;
    float xv[5];
    float sum = 0.f, sumsq = 0.f;
    #pragma unroll
    for (int it = 0; it < 5; ++it) {
        int d = tid + (it << 8);
        float x = 0.f;
        if (d < 1152) {
            x = (float)Hi[d] + (float)Hj[1152 + d] + kb[d];
            sum += x; sumsq += x * x;
        }
        xv[it] = x;
    }
    #pragma unroll
    for (int off = 32; off > 0; off >>= 1) {
        sum += __shfl_xor(sum, off, 64);
        sumsq += __shfl_xor(sumsq, off, 64);
    }
    __shared__ float s1[4], s2[4], sr[4][4];
    const int wid = tid >> 6;
    if ((tid & 63) == 0) { s1[wid] = sum; s2[wid] = sumsq; }
    __syncthreads();
    sum = s1[0] + s1[1] + s1[2] + s1[3];
    sumsq = s2[0] + s2[1] + s2[2] + s2[3];
    const float mu = sum * (1.f / 1152.f);
    const float var = sumsq * (1.f / 1152.f) - mu * mu;
    const float rs = rsqrtf(var + 1e-5f);
    float g_ = 0.f, k_ = 0.f, b_ = 0.f, v_ = 0.f;
    #pragma unroll
    for (int it = 0; it < 5; ++it) {
        int d = tid + (it << 8);
        if (d < 1152) {
            float gm = gamma[d];
            float sk = (xv[it] - mu) * rs * gm + beta[d];
            outK[d] = (bf16)(gm * sk);
            g_ += gm * sk;
            k_ += kb[d] * gm * sk;
            b_ += beta[d] * sk;
            float sv = (float)Hi[2304 + d] + (float)Hj[3456 + d] + vb[d];
            outV[d] = (bf16)sv;
            v_ += vb[d] * sv;
        }
    }
    #pragma unroll
    for (int off = 32; off > 0; off >>= 1) {
        g_ += __shfl_xor(g_, off, 64);
        k_ += __shfl_xor(k_, off, 64);
        b_ += __shfl_xor(b_, off, 64);
        v_ += __shfl_xor(v_, off, 64);
    }
    if ((tid & 63) == 0) { sr[wid][0] = g_; sr[wid][1] = k_; sr[wid][2] = b_; sr[wid][3] = v_; }
    __syncthreads();
    if (tid == 0) {
        gd[u]   = sr[0][0] + sr[1][0] + sr[2][0] + sr[3][0];
        kbd[u]  = sr[0][1] + sr[1][1] + sr[2][1] + sr[3][1];
        bd2[u]  = sr[0][2] + sr[1][2] + sr[2][2] + sr[3][2];
        bdot[u] = sr[0][3] + sr[1][3] + sr[2][3] + sr[3][3];
    }
}

// ---------------------------------------------------------------------------
// Per-query frame-dot stats.  Blocks 0..499: K-side -> MU[m], RS[m] for the
// 28 tuple rows of query q.  Blocks 500..999: V-side -> QS[q].
__global__ __launch_bounds__(256) void row_stats(
    const bf16* __restrict__ H, const float* __restrict__ kb,
    const float* __restrict__ vb, float* __restrict__ MU,
    float* __restrict__ RS, float* __restrict__ QS)
{
    const bool kside = (int)blockIdx.x < 500;
    const int q = kside ? blockIdx.x : blockIdx.x - 500;
    const int co = kside ? 0 : 2304;
    const float* bias = kside ? kb : vb;
    const int tid = threadIdx.x;
    __shared__ __align__(16) bf16 Ft[8 * 1152];
    __shared__ __align__(16) bf16 Fb[8 * 1152];
    __shared__ float Sa[8], Qa[8], Ca[8], Sb_[8], Qb_[8], Cb_[8], Pp[28], Sk2[2];
    for (int idx = tid; idx < 1152; idx += 256) {
        int row = idx / 144, col = (idx - row * 144) << 3;
        const bf16* src = H + (long)((q << 3) + row) * 4608 + co;
        *(bf16x8*)(Ft + row * 1152 + col) = *(const bf16x8*)(src + col);
        *(bf16x8*)(Fb + row * 1152 + col) = *(const bf16x8*)(src + 1152 + col);
    }
    __syncthreads();
    const int wid = tid >> 6, lane = tid & 63;
    for (int task = wid; task < 45; task += 4) {
        float s0 = 0.f, s1 = 0.f, s2 = 0.f;
        if (task < 16) {
            const bf16* p = (task < 8) ? (Ft + task * 1152) : (Fb + (task - 8) * 1152);
            for (int c = lane << 3; c < 1152; c += 512) {
                bf16x8 v = *(const bf16x8*)(p + c);
                #pragma unroll
                for (int k = 0; k < 8; ++k) {
                    float f = (float)v[k];
                    s0 += f; s1 += f * f; s2 += f * bias[c + k];
                }
            }
        } else if (task < 44) {
            int t = task - 16;
            const bf16* pa = Ft + c_T0[t] * 1152;
            const bf16* pb = Fb + c_T1[t] * 1152;
            for (int c = lane << 3; c < 1152; c += 512) {
                bf16x8 a = *(const bf16x8*)(pa + c);
                bf16x8 b = *(const bf16x8*)(pb + c);
                #pragma unroll
                for (int k = 0; k < 8; ++k) s0 += (float)a[k] * (float)b[k];
            }
        } else {
            for (int c = lane << 3; c < 1152; c += 512) {
                #pragma unroll
                for (int k = 0; k < 8; ++k) { float f = bias[c + k]; s0 += f; s1 += f * f; }
            }
        }
        #pragma unroll
        for (int off = 32; off > 0; off >>= 1) {
            s0 += __shfl_xor(s0, off, 64);
            s1 += __shfl_xor(s1, off, 64);
            s2 += __shfl_xor(s2, off, 64);
        }
        if (lane == 0) {
            if (task < 8)       { Sa[task] = s0; Qa[task] = s1; Ca[task] = s2; }
            else if (task < 16) { Sb_[task - 8] = s0; Qb_[task - 8] = s1; Cb_[task - 8] = s2; }
            else if (task < 44) Pp[task - 16] = s0;
            else                { Sk2[0] = s0; Sk2[1] = s1; }
        }
    }
    __syncthreads();
    if (kside) {
        if (tid < 28) {
            int i = c_T0[tid], j = c_T1[tid];
            float mu = (Sa[i] + Sb_[j] + Sk2[0]) * (1.f / 1152.f);
            float ex2 = (Qa[i] + Qb_[j] + Sk2[1] + 2.f * (Pp[tid] + Ca[i] + Cb_[j])) * (1.f / 1152.f);
            float var = ex2 - mu * mu;
            int m = q * 28 + tid;
            MU[m] = mu;
            RS[m] = rsqrtf(var + 1e-5f);
        }
    } else {
        if (tid < 64) {
            float term = 0.f;
            if (lane < 28) {
                int i = c_T0[lane], j = c_T1[lane];
                term = Qa[i] + Qb_[j] + Sk2[1] + 2.f * (Pp[lane] + Ca[i] + Cb_[j]);
            }
            #pragma unroll
            for (int off = 32; off > 0; off >>= 1) term += __shfl_xor(term, off, 64);
            if (lane == 0) QS[q] = term;
        }
    }
}

// ---------------------------------------------------------------------------
// Assemble scores from per-frame products + LN stats, softmax per class,
// write attn (bf16).  One block per tuple-row; 5 waves = 5 classes.
__global__ __launch_bounds__(320) void assemble_softmax(
    const float* __restrict__ Fkt, const float* __restrict__ Fkb,
    const float* __restrict__ MU, const float* __restrict__ RS,
    const float* __restrict__ gd, const float* __restrict__ kbd,
    const float* __restrict__ bd2, bf16* __restrict__ attn)
{
    const int m = blockIdx.x, tid = threadIdx.x;
    bf16* arow = attn + (long)m * 768;
    if (m >= 14000) {
        for (int d = tid; d < 768; d += 320) arow[d] = (bf16)0.f;
        return;
    }
    if (tid < 68) arow[700 + tid] = (bf16)0.f;
    const int q = m / 28, t = m - q * 28;
    const float* ft = Fkt + (long)((q << 3) + c_T0[t]) * 768;
    const float* fb = Fkb + (long)((q << 3) + c_T1[t]) * 768;
    const float mu = MU[m], rs = RS[m];
    const int w = tid >> 6, lane = tid & 63;
    const int base = w * 140;
    const float sc = 0.029462782549439484f; // 1/sqrt(1152)
    int u0 = base + lane, u1 = base + 64 + lane, u2 = base + 128 + lane;
    float v0 = (rs * (ft[u0] + fb[u0] + kbd[u0] - mu * gd[u0]) + bd2[u0]) * sc;
    float v1 = (rs * (ft[u1] + fb[u1] + kbd[u1] - mu * gd[u1]) + bd2[u1]) * sc;
    float v2 = (lane < 12)
             ? (rs * (ft[u2] + fb[u2] + kbd[u2] - mu * gd[u2]) + bd2[u2]) * sc
             : -1e30f;
    float mx = fmaxf(fmaxf(v0, v1), v2);
    #pragma unroll
    for (int off = 32; off > 0; off >>= 1) mx = fmaxf(mx, __shfl_xor(mx, off, 64));
    float e0 = __expf(v0 - mx), e1 = __expf(v1 - mx);
    float e2 = (lane < 12) ? __expf(v2 - mx) : 0.f;
    float s = e0 + e1 + e2;
    #pragma unroll
    for (int off = 32; off > 0; off >>= 1) s += __shfl_xor(s, off, 64);
    const float inv = 1.f / s;
    bf16* aw = arow + base;
    aw[lane] = (bf16)(e0 * inv);
    aw[64 + lane] = (bf16)(e1 * inv);
    if (lane < 12) aw[128 + lane] = (bf16)(e2 * inv);
}

// ---------------------------------------------------------------------------
// dist[c][q] += sum_u a*(attnG - 2W),  W[m,u] = Fvt[fi,u] + Fvb[fj,u] + bdot[u].
__global__ __launch_bounds__(256) void final_dist(
    const bf16* __restrict__ attn, const bf16* __restrict__ attnG,
    const float* __restrict__ FG, const float* __restrict__ bdot,
    float* __restrict__ dist)
{
    const int w = threadIdx.x >> 6, lane = threadIdx.x & 63;
    const int m = blockIdx.x * 4 + w; // < 14000
    const int q = m / 28, t = m - q * 28;
    const int fi = (q << 3) + c_T0[t], fj = (q << 3) + c_T1[t];
    const bf16* ar = attn + (long)m * 768;
    const bf16* gr = attnG + (long)m * 768;
    const float* ft = FG + (long)(8448 + fi) * 768;
    const float* fb = FG + (long)(12672 + fj) * 768;
    #pragma unroll
    for (int c = 0; c < 5; ++c) {
        const int base = c * 140;
        float s = 0.f;
        {
            int u = base + lane;
            float wv = ft[u] + fb[u] + bdot[u];
            s += (float)ar[u] * ((float)gr[u] - 2.f * wv);
        }
        {
            int u = base + 64 + lane;
            float wv = ft[u] + fb[u] + bdot[u];
            s += (float)ar[u] * ((float)gr[u] - 2.f * wv);
        }
        if (lane < 12) {
            int u = base + 128 + lane;
            float wv = ft[u] + fb[u] + bdot[u];
            s += (float)ar[u] * ((float)gr[u] - 2.f * wv);
        }
        #pragma unroll
        for (int off = 32; off > 0; off >>= 1) s += __shfl_xor(s, off, 64);
        if (lane == 0) atomicAdd(&dist[c * 500 + q], s);
    }
}

// ---------------------------------------------------------------------------
__global__ void finalize(const float* __restrict__ dist, const float* __restrict__ QS,
                         const float* __restrict__ gt, const float* __restrict__ tw,
                         float* __restrict__ out)
{
    int i = blockIdx.x * 256 + threadIdx.x;
    if (i < 2500) {
        int q = i / 5, c = i - q * 5;
        out[i] = -(dist[c * 500 + q] + QS[q]) * (gt[0] * tw[0] * (1.f / 28.f));
    }
}

// ---------------------------------------------------------------------------
extern "C" void kernel_launch(void* const* d_in, const int* in_sizes, int n_in,
                              void* d_out, int out_size, void* d_ws, size_t ws_size,
                              hipStream_t stream)
{
    const float* support = (const float*)d_in[0];
    const float* queries = (const float*)d_in[2];
    const float* kw      = (const float*)d_in[3];
    const float* kb      = (const float*)d_in[4];
    const float* vw      = (const float*)d_in[5];
    const float* vb      = (const float*)d_in[6];
    const float* gamma   = (const float*)d_in[7];
    const float* beta    = (const float*)d_in[8];
    const float* gt      = (const float*)d_in[9];
    const float* tw      = (const float*)d_in[10];
    float* out = (float*)d_out;

    char* ws = (char*)d_ws;
    size_t off = 0;
    auto alloc = [&](size_t b) { char* p = ws + off; off += (b + 255) & ~(size_t)255; return p; };
    bf16* X      = (bf16*)alloc(4224ull * 2048 * 2);
    bf16* Wp     = (bf16*)alloc(4608ull * 2048 * 2);
    // union: H [4224x4608 bf16, 38.9MB] first; then attn+attnG [21.6MB each]
    char* uni    = alloc(14080ull * 768 * 4);
    bf16* H      = (bf16*)uni;
    bf16* attn   = (bf16*)uni;
    bf16* attnG  = (bf16*)(uni + 14080ull * 768 * 2);
    // FG: [Fkt(4224); Fkb(4224); Fvt(4224); Fvb(4224)] x 768 f32
    float* FG    = (float*)alloc(16896ull * 768 * 4);
    bf16* Bk     = (bf16*)alloc(768ull * 1152 * 2);
    bf16* svs    = (bf16*)alloc(768ull * 1152 * 2);
    bf16* Gb     = (bf16*)alloc(768ull * 768 * 2);
    float* MU    = (float*)alloc(14000ull * 4);
    float* RS    = (float*)alloc(14000ull * 4);
    float* gd    = (float*)alloc(768 * 4);
    float* kbd   = (float*)alloc(768 * 4);
    float* bd2   = (float*)alloc(768 * 4);
    float* bdot  = (float*)alloc(768 * 4);
    float* QS    = (float*)alloc(500 * 4);
    float* dist  = (float*)alloc(5 * 500 * 4);

    hipMemsetAsync(dist, 0, 5 * 500 * 4, stream);
    fill_pack<<<4224 + 9216, 256, 0, stream>>>(queries, support, kw, vw, X, Wp);
    // H[4224][4608] = X x Wp^T  (bf16 out)
    gemm_bt<bf16><<<33 * 36, 256, 0, stream>>>(X, 2048, Wp, 2048, H, 4608, 2048, 1.f, 36);
    proj_support<<<768, 256, 0, stream>>>(H, kb, vb, gamma, beta, Bk, svs, gd, kbd, bd2, bdot);
    row_stats<<<1000, 256, 0, stream>>>(H, kb, vb, MU, RS, QS);
    gemm_frames<<<828, 256, 0, stream>>>(H, Bk, svs, FG, Gb);
    assemble_softmax<<<14080, 320, 0, stream>>>(FG, FG + 4224ull * 768, MU, RS, gd, kbd, bd2, attn);
    // attnG[14080][768] = attn x Gb^T
    gemm_bt<bf16><<<110 * 6, 256, 0, stream>>>(attn, 768, Gb, 768, attnG, 768, 768, 1.f, 6);
    final_dist<<<3500, 256, 0, stream>>>(attn, attnG, FG, bdot, dist);
    finalize<<<10, 256, 0, stream>>>(dist, QS, gt, tw, out);
}

// Round 6
// 419.152 us; speedup vs baseline: 1.2660x; 1.0104x over previous
//
#include <hip/hip_runtime.h>

typedef __bf16 bf16;
typedef __attribute__((ext_vector_type(8))) __bf16 bf16x8;
typedef __attribute__((ext_vector_type(4))) float f32x4;

#define AS1 __attribute__((address_space(1)))
#define AS3 __attribute__((address_space(3)))

// tuple tables: combinations(range(8), 2), lexicographic
__device__ __constant__ int c_T0[28] = {0,0,0,0,0,0,0,1,1,1,1,1,1,2,2,2,2,2,3,3,3,3,4,4,4,5,5,6};
__device__ __constant__ int c_T1[28] = {1,2,3,4,5,6,7,2,3,4,5,6,7,3,4,5,6,7,4,5,6,7,5,6,7,6,7,7};

// ---------------------------------------------------------------------------
// Merged: blocks < 4224 fill X (frames + PE); blocks >= 4224 pack Wp.
__global__ __launch_bounds__(256) void fill_pack(
    const float* __restrict__ queries, const float* __restrict__ support,
    const float* __restrict__ kw, const float* __restrict__ vw,
    bf16* __restrict__ X, bf16* __restrict__ Wp)
{
    __shared__ float t[32][33];
    const int tid = threadIdx.x;
    if (blockIdx.x < 4224) {
        const int f = blockIdx.x;
        bf16* row = X + (long)f * 2048;
        const int d0 = tid << 3;
        if (f >= 4200) {
            bf16x8 z;
            #pragma unroll
            for (int i = 0; i < 8; ++i) z[i] = (bf16)0.f;
            *(bf16x8*)(row + d0) = z;
            return;
        }
        const float* src = (f < 4000) ? (queries + (long)f * 2048)
                                      : (support + (long)(f - 4000) * 2048);
        const int s = f & 7;
        bf16x8 o;
        #pragma unroll
        for (int i = 0; i < 8; ++i) {
            int d = d0 + i;
            float dv = __expf((float)(d >> 1) * -0.008994473019508f); // -ln(1e4)/1024
            float ang = (float)s * dv;
            float pe = (d & 1) ? __cosf(ang) : __sinf(ang);
            o[i] = (bf16)(src[d] + pe);
        }
        *(bf16x8*)(row + d0) = o;
    } else {
        const int b = blockIdx.x - 4224;
        const int k0 = (b & 63) << 5, n0g = (b >> 6) << 5;
        const int tx = tid & 31, ty = tid >> 5;
        const int j = n0g / 1152, nc = n0g % 1152;
        const float* src = ((j < 2) ? kw : vw) + (long)(((j & 1) << 11) + k0) * 1152 + nc;
        #pragma unroll
        for (int i = 0; i < 4; ++i)
            t[ty + (i << 3)][tx] = src[(long)(ty + (i << 3)) * 1152 + tx];
        __syncthreads();
        #pragma unroll
        for (int i = 0; i < 4; ++i)
            Wp[(long)(n0g + ty + (i << 3)) * 2048 + k0 + tx] = (bf16)t[tx][ty + (i << 3)];
    }
}

// ---------------------------------------------------------------------------
// C[M,N] = scale * A[M,K](bf16, lda) x B[N,K](bf16, ldb)^T.  Row-major block
// order (no swizzle — R4 showed swizzle hurts locality here).
template <typename OutT>
__global__ __launch_bounds__(256) void gemm_bt(
    const bf16* __restrict__ A, long lda, const bf16* __restrict__ B, long ldb,
    OutT* __restrict__ C, int N, int K, float scale, int tiles_n)
{
    __shared__ __align__(16) bf16 lA[128 * 32];
    __shared__ __align__(16) bf16 lB[128 * 32];
    const int tid = threadIdx.x;
    const int wid = tid >> 6, lane = tid & 63;
    const int wm = (wid >> 1) << 6, wn = (wid & 1) << 6;
    const int quad = lane >> 4, l16 = lane & 15;
    const int tm = blockIdx.x / tiles_n, tn = blockIdx.x % tiles_n;
    const int m0 = tm << 7, n0 = tn << 7;
    const bf16* Abase = A + (long)m0 * lda;

    f32x4 acc[4][4];
    #pragma unroll
    for (int i = 0; i < 4; ++i)
        #pragma unroll
        for (int j = 0; j < 4; ++j)
            #pragma unroll
            for (int r = 0; r < 4; ++r) acc[i][j][r] = 0.f;

    const int srow = lane >> 2, scol = (lane & 3) << 3;
    for (int kk = 0; kk < K; kk += 32) {
        __syncthreads();
        #pragma unroll
        for (int p = 0; p < 2; ++p) {
            const int rbase = (wid << 5) + (p << 4);
            const bf16* ga = Abase + (long)(rbase + srow) * lda + kk + scol;
            const bf16* gb = B + (long)(n0 + rbase + srow) * ldb + kk + scol;
            __builtin_amdgcn_global_load_lds((const AS1 unsigned int*)ga,
                                             (AS3 unsigned int*)(lA + rbase * 32), 16, 0, 0);
            __builtin_amdgcn_global_load_lds((const AS1 unsigned int*)gb,
                                             (AS3 unsigned int*)(lB + rbase * 32), 16, 0, 0);
        }
        __builtin_amdgcn_s_waitcnt(0);
        __syncthreads();
        bf16x8 af[4], bfr[4];
        #pragma unroll
        for (int i = 0; i < 4; ++i)
            af[i] = *(const bf16x8*)(lA + (wm + (i << 4) + l16) * 32 + (quad << 3));
        #pragma unroll
        for (int j = 0; j < 4; ++j)
            bfr[j] = *(const bf16x8*)(lB + (wn + (j << 4) + l16) * 32 + (quad << 3));
        #pragma unroll
        for (int i = 0; i < 4; ++i)
            #pragma unroll
            for (int j = 0; j < 4; ++j)
                acc[i][j] = __builtin_amdgcn_mfma_f32_16x16x32_bf16(af[i], bfr[j], acc[i][j], 0, 0, 0);
    }
    #pragma unroll
    for (int i = 0; i < 4; ++i) {
        const int row = m0 + wm + (i << 4) + (quad << 2);
        #pragma unroll
        for (int j = 0; j < 4; ++j) {
            const int col = n0 + wn + (j << 4) + l16;
            OutT* cp = C + (long)row * N + col;
            #pragma unroll
            for (int r = 0; r < 4; ++r) cp[(long)r * N] = (OutT)(acc[i][j][r] * scale);
        }
    }
}

// ---------------------------------------------------------------------------
// Per-frame GEMMs in one launch.  828 blocks:
//   bid <  792: seg = bid/198 in {0:Fkt, 1:Fkb, 2:Fvt, 3:Fvb};
//               A = H col-segment seg*1152 (lda 4608), B = (seg<2 ? Bk : svs),
//               C = FG + seg*4224 rows (bf16).
//   bid >= 792: Gram = svs x svs^T, block-diag masked, bf16 -> Gb.
__global__ __launch_bounds__(256) void gemm_frames(
    const bf16* __restrict__ H, const bf16* __restrict__ Bk,
    const bf16* __restrict__ svs, bf16* __restrict__ FG, bf16* __restrict__ Gb)
{
    __shared__ __align__(16) bf16 lA[128 * 32];
    __shared__ __align__(16) bf16 lB[128 * 32];
    const int tid = threadIdx.x;
    const int wid = tid >> 6, lane = tid & 63;
    const int wm = (wid >> 1) << 6, wn = (wid & 1) << 6;
    const int quad = lane >> 4, l16 = lane & 15;
    const bool gram = (int)blockIdx.x >= 792;
    int seg = 4, tm, tn;
    const bf16* Abase;
    long la;
    const bf16* B;
    if (!gram) {
        seg = blockIdx.x / 198;
        int r = blockIdx.x % 198;
        tm = r / 6; tn = r % 6;
        Abase = H + seg * 1152 + (long)(tm << 7) * 4608;
        la = 4608;
        B = (seg < 2) ? Bk : svs;
    } else {
        int r = blockIdx.x - 792;
        tm = r / 6; tn = r % 6;
        Abase = svs + (long)(tm << 7) * 1152;
        la = 1152;
        B = svs;
    }
    const int n0 = tn << 7;

    f32x4 acc[4][4];
    #pragma unroll
    for (int i = 0; i < 4; ++i)
        #pragma unroll
        for (int j = 0; j < 4; ++j)
            #pragma unroll
            for (int r = 0; r < 4; ++r) acc[i][j][r] = 0.f;

    const int srow = lane >> 2, scol = (lane & 3) << 3;
    for (int kk = 0; kk < 1152; kk += 32) {
        __syncthreads();
        #pragma unroll
        for (int p = 0; p < 2; ++p) {
            const int rbase = (wid << 5) + (p << 4);
            const bf16* ga = Abase + (long)(rbase + srow) * la + kk + scol;
            const bf16* gb = B + (long)(n0 + rbase + srow) * 1152 + kk + scol;
            __builtin_amdgcn_global_load_lds((const AS1 unsigned int*)ga,
                                             (AS3 unsigned int*)(lA + rbase * 32), 16, 0, 0);
            __builtin_amdgcn_global_load_lds((const AS1 unsigned int*)gb,
                                             (AS3 unsigned int*)(lB + rbase * 32), 16, 0, 0);
        }
        __builtin_amdgcn_s_waitcnt(0);
        __syncthreads();
        bf16x8 af[4], bfr[4];
        #pragma unroll
        for (int i = 0; i < 4; ++i)
            af[i] = *(const bf16x8*)(lA + (wm + (i << 4) + l16) * 32 + (quad << 3));
        #pragma unroll
        for (int j = 0; j < 4; ++j)
            bfr[j] = *(const bf16x8*)(lB + (wn + (j << 4) + l16) * 32 + (quad << 3));
        #pragma unroll
        for (int i = 0; i < 4; ++i)
            #pragma unroll
            for (int j = 0; j < 4; ++j)
                acc[i][j] = __builtin_amdgcn_mfma_f32_16x16x32_bf16(af[i], bfr[j], acc[i][j], 0, 0, 0);
    }
    #pragma unroll
    for (int i = 0; i < 4; ++i) {
        const int rloc = (tm << 7) + wm + (i << 4) + (quad << 2);
        #pragma unroll
        for (int j = 0; j < 4; ++j) {
            const int col = n0 + wn + (j << 4) + l16;
            #pragma unroll
            for (int r = 0; r < 4; ++r) {
                const int row = rloc + r;
                if (!gram) {
                    FG[(long)(seg * 4224 + row) * 768 + col] = (bf16)acc[i][j][r];
                } else {
                    bool keep = (row < 700) && (col < 700) && (row / 140 == col / 140);
                    Gb[(long)row * 768 + col] = keep ? (bf16)acc[i][j][r] : (bf16)0.f;
                }
            }
        }
    }
}

// ---------------------------------------------------------------------------
// Merged support projection + per-query stats (shared-mem union).
// Blocks 0..767: support tuple rows -> Bk = gamma.*sks, svs; per-row scalars
//   gd/kbd/bd2/bdot.
// Blocks 768..1267 (q = bid-768):   K-side frame dots -> MU[m], RS[m].
// Blocks 1268..1767 (q = bid-1268): V-side frame dots -> QS[q].
__global__ __launch_bounds__(256) void support_stats(
    const bf16* __restrict__ H, const float* __restrict__ kb,
    const float* __restrict__ vb, const float* __restrict__ gamma,
    const float* __restrict__ beta,
    bf16* __restrict__ Bk, bf16* __restrict__ svs,
    float* __restrict__ gd, float* __restrict__ kbd,
    float* __restrict__ bd2, float* __restrict__ bdot,
    float* __restrict__ MU, float* __restrict__ RS, float* __restrict__ QS)
{
    __shared__ __align__(16) char smem[2 * 9216 * 2 + 512];
    const int tid = threadIdx.x;
    const int wid = tid >> 6, lane = tid & 63;
    if ((int)blockIdx.x < 768) {
        // ---- support projection ----
        const int u = blockIdx.x;
        bf16* outK = Bk + (long)u * 1152;
        bf16* outV = svs + (long)u * 1152;
        if (u >= 700) {
            for (int d = tid; d < 1152; d += 256) { outK[d] = (bf16)0.f; outV[d] = (bf16)0.f; }
            if (tid == 0) { gd[u] = 0.f; kbd[u] = 0.f; bd2[u] = 0.f; bdot[u] = 0.f; }
            return;
        }
        float* s1 = (float*)smem;        // [4]
        float* s2 = s1 + 4;              // [4]
        float* sr = s2 + 4;              // [4][4]
        const int n = u / 28, t = u - n * 28;
        const int fi = 4000 + (n << 3) + c_T0[t];
        const int fj = 4000 + (n << 3) + c_T1[t];
        const bf16* Hi = H + (long)fi * 4608;
        const bf16* Hj = H + (long)fj * 4608;
        float xv[5];
        float sum = 0.f, sumsq = 0.f;
        #pragma unroll
        for (int it = 0; it < 5; ++it) {
            int d = tid + (it << 8);
            float x = 0.f;
            if (d < 1152) {
                x = (float)Hi[d] + (float)Hj[1152 + d] + kb[d];
                sum += x; sumsq += x * x;
            }
            xv[it] = x;
        }
        #pragma unroll
        for (int off = 32; off > 0; off >>= 1) {
            sum += __shfl_xor(sum, off, 64);
            sumsq += __shfl_xor(sumsq, off, 64);
        }
        if ((tid & 63) == 0) { s1[wid] = sum; s2[wid] = sumsq; }
        __syncthreads();
        sum = s1[0] + s1[1] + s1[2] + s1[3];
        sumsq = s2[0] + s2[1] + s2[2] + s2[3];
        const float mu = sum * (1.f / 1152.f);
        const float var = sumsq * (1.f / 1152.f) - mu * mu;
        const float rs = rsqrtf(var + 1e-5f);
        float g_ = 0.f, k_ = 0.f, b_ = 0.f, v_ = 0.f;
        #pragma unroll
        for (int it = 0; it < 5; ++it) {
            int d = tid + (it << 8);
            if (d < 1152) {
                float gm = gamma[d];
                float sk = (xv[it] - mu) * rs * gm + beta[d];
                outK[d] = (bf16)(gm * sk);
                g_ += gm * sk;
                k_ += kb[d] * gm * sk;
                b_ += beta[d] * sk;
                float sv = (float)Hi[2304 + d] + (float)Hj[3456 + d] + vb[d];
                outV[d] = (bf16)sv;
                v_ += vb[d] * sv;
            }
        }
        #pragma unroll
        for (int off = 32; off > 0; off >>= 1) {
            g_ += __shfl_xor(g_, off, 64);
            k_ += __shfl_xor(k_, off, 64);
            b_ += __shfl_xor(b_, off, 64);
            v_ += __shfl_xor(v_, off, 64);
        }
        if ((tid & 63) == 0) { sr[wid * 4 + 0] = g_; sr[wid * 4 + 1] = k_; sr[wid * 4 + 2] = b_; sr[wid * 4 + 3] = v_; }
        __syncthreads();
        if (tid == 0) {
            gd[u]   = sr[0] + sr[4] + sr[8]  + sr[12];
            kbd[u]  = sr[1] + sr[5] + sr[9]  + sr[13];
            bd2[u]  = sr[2] + sr[6] + sr[10] + sr[14];
            bdot[u] = sr[3] + sr[7] + sr[11] + sr[15];
        }
        return;
    }
    // ---- per-query frame-dot stats ----
    const int s_ = blockIdx.x - 768;
    const bool kside = s_ < 500;
    const int q = kside ? s_ : s_ - 500;
    const int co = kside ? 0 : 2304;
    const float* bias = kside ? kb : vb;
    bf16* Ft = (bf16*)smem;
    bf16* Fb = Ft + 9216;
    float* fl = (float*)(smem + 36864);
    float* Sa = fl;        // [8]
    float* Qa = fl + 8;    // [8]
    float* Ca = fl + 16;   // [8]
    float* Sb_ = fl + 24;  // [8]
    float* Qb_ = fl + 32;  // [8]
    float* Cb_ = fl + 40;  // [8]
    float* Pp = fl + 48;   // [28]
    float* Sk2 = fl + 76;  // [2]
    for (int idx = tid; idx < 1152; idx += 256) {
        int row = idx / 144, col = (idx - row * 144) << 3;
        const bf16* src = H + (long)((q << 3) + row) * 4608 + co;
        *(bf16x8*)(Ft + row * 1152 + col) = *(const bf16x8*)(src + col);
        *(bf16x8*)(Fb + row * 1152 + col) = *(const bf16x8*)(src + 1152 + col);
    }
    __syncthreads();
    for (int task = wid; task < 45; task += 4) {
        float s0 = 0.f, s1v = 0.f, s2v = 0.f;
        if (task < 16) {
            const bf16* p = (task < 8) ? (Ft + task * 1152) : (Fb + (task - 8) * 1152);
            for (int c = lane << 3; c < 1152; c += 512) {
                bf16x8 v = *(const bf16x8*)(p + c);
                #pragma unroll
                for (int k = 0; k < 8; ++k) {
                    float f = (float)v[k];
                    s0 += f; s1v += f * f; s2v += f * bias[c + k];
                }
            }
        } else if (task < 44) {
            int t = task - 16;
            const bf16* pa = Ft + c_T0[t] * 1152;
            const bf16* pb = Fb + c_T1[t] * 1152;
            for (int c = lane << 3; c < 1152; c += 512) {
                bf16x8 a = *(const bf16x8*)(pa + c);
                bf16x8 b = *(const bf16x8*)(pb + c);
                #pragma unroll
                for (int k = 0; k < 8; ++k) s0 += (float)a[k] * (float)b[k];
            }
        } else {
            for (int c = lane << 3; c < 1152; c += 512) {
                #pragma unroll
                for (int k = 0; k < 8; ++k) { float f = bias[c + k]; s0 += f; s1v += f * f; }
            }
        }
        #pragma unroll
        for (int off = 32; off > 0; off >>= 1) {
            s0 += __shfl_xor(s0, off, 64);
            s1v += __shfl_xor(s1v, off, 64);
            s2v += __shfl_xor(s2v, off, 64);
        }
        if (lane == 0) {
            if (task < 8)       { Sa[task] = s0; Qa[task] = s1v; Ca[task] = s2v; }
            else if (task < 16) { Sb_[task - 8] = s0; Qb_[task - 8] = s1v; Cb_[task - 8] = s2v; }
            else if (task < 44) Pp[task - 16] = s0;
            else                { Sk2[0] = s0; Sk2[1] = s1v; }
        }
    }
    __syncthreads();
    if (kside) {
        if (tid < 28) {
            int i = c_T0[tid], j = c_T1[tid];
            float mu = (Sa[i] + Sb_[j] + Sk2[0]) * (1.f / 1152.f);
            float ex2 = (Qa[i] + Qb_[j] + Sk2[1] + 2.f * (Pp[tid] + Ca[i] + Cb_[j])) * (1.f / 1152.f);
            float var = ex2 - mu * mu;
            int m = q * 28 + tid;
            MU[m] = mu;
            RS[m] = rsqrtf(var + 1e-5f);
        }
    } else {
        if (tid < 64) {
            float term = 0.f;
            if (lane < 28) {
                int i = c_T0[lane], j = c_T1[lane];
                term = Qa[i] + Qb_[j] + Sk2[1] + 2.f * (Pp[lane] + Ca[i] + Cb_[j]);
            }
            #pragma unroll
            for (int off = 32; off > 0; off >>= 1) term += __shfl_xor(term, off, 64);
            if (lane == 0) QS[q] = term;
        }
    }
}

// ---------------------------------------------------------------------------
// Assemble scores from per-frame products (bf16) + LN stats, softmax per
// class, write attn (bf16).  One block per tuple-row; 5 waves = 5 classes.
__global__ __launch_bounds__(320) void assemble_softmax(
    const bf16* __restrict__ Fkt, const bf16* __restrict__ Fkb,
    const float* __restrict__ MU, const float* __restrict__ RS,
    const float* __restrict__ gd, const float* __restrict__ kbd,
    const float* __restrict__ bd2, bf16* __restrict__ attn)
{
    const int m = blockIdx.x, tid = threadIdx.x;
    bf16* arow = attn + (long)m * 768;
    if (m >= 14000) {
        for (int d = tid; d < 768; d += 320) arow[d] = (bf16)0.f;
        return;
    }
    if (tid < 68) arow[700 + tid] = (bf16)0.f;
    const int q = m / 28, t = m - q * 28;
    const bf16* ft = Fkt + (long)((q << 3) + c_T0[t]) * 768;
    const bf16* fb = Fkb + (long)((q << 3) + c_T1[t]) * 768;
    const float mu = MU[m], rs = RS[m];
    const int w = tid >> 6, lane = tid & 63;
    const int base = w * 140;
    const float sc = 0.029462782549439484f; // 1/sqrt(1152)
    int u0 = base + lane, u1 = base + 64 + lane, u2 = base + 128 + lane;
    float v0 = (rs * ((float)ft[u0] + (float)fb[u0] + kbd[u0] - mu * gd[u0]) + bd2[u0]) * sc;
    float v1 = (rs * ((float)ft[u1] + (float)fb[u1] + kbd[u1] - mu * gd[u1]) + bd2[u1]) * sc;
    float v2 = (lane < 12)
             ? (rs * ((float)ft[u2] + (float)fb[u2] + kbd[u2] - mu * gd[u2]) + bd2[u2]) * sc
             : -1e30f;
    float mx = fmaxf(fmaxf(v0, v1), v2);
    #pragma unroll
    for (int off = 32; off > 0; off >>= 1) mx = fmaxf(mx, __shfl_xor(mx, off, 64));
    float e0 = __expf(v0 - mx), e1 = __expf(v1 - mx);
    float e2 = (lane < 12) ? __expf(v2 - mx) : 0.f;
    float s = e0 + e1 + e2;
    #pragma unroll
    for (int off = 32; off > 0; off >>= 1) s += __shfl_xor(s, off, 64);
    const float inv = 1.f / s;
    bf16* aw = arow + base;
    aw[lane] = (bf16)(e0 * inv);
    aw[64 + lane] = (bf16)(e1 * inv);
    if (lane < 12) aw[128 + lane] = (bf16)(e2 * inv);
}

// ---------------------------------------------------------------------------
// dist[c][q] += sum_u a*(attnG - 2W),  W[m,u] = Fvt[fi,u] + Fvb[fj,u] + bdot[u].
__global__ __launch_bounds__(256) void final_dist(
    const bf16* __restrict__ attn, const bf16* __restrict__ attnG,
    const bf16* __restrict__ FG, const float* __restrict__ bdot,
    float* __restrict__ dist)
{
    const int w = threadIdx.x >> 6, lane = threadIdx.x & 63;
    const int m = blockIdx.x * 4 + w; // < 14000
    const int q = m / 28, t = m - q * 28;
    const int fi = (q << 3) + c_T0[t], fj = (q << 3) + c_T1[t];
    const bf16* ar = attn + (long)m * 768;
    const bf16* gr = attnG + (long)m * 768;
    const bf16* ft = FG + (long)(8448 + fi) * 768;
    const bf16* fb = FG + (long)(12672 + fj) * 768;
    #pragma unroll
    for (int c = 0; c < 5; ++c) {
        const int base = c * 140;
        float s = 0.f;
        {
            int u = base + lane;
            float wv = (float)ft[u] + (float)fb[u] + bdot[u];
            s += (float)ar[u] * ((float)gr[u] - 2.f * wv);
        }
        {
            int u = base + 64 + lane;
            float wv = (float)ft[u] + (float)fb[u] + bdot[u];
            s += (float)ar[u] * ((float)gr[u] - 2.f * wv);
        }
        if (lane < 12) {
            int u = base + 128 + lane;
            float wv = (float)ft[u] + (float)fb[u] + bdot[u];
            s += (float)ar[u] * ((float)gr[u] - 2.f * wv);
        }
        #pragma unroll
        for (int off = 32; off > 0; off >>= 1) s += __shfl_xor(s, off, 64);
        if (lane == 0) atomicAdd(&dist[c * 500 + q], s);
    }
}

// ---------------------------------------------------------------------------
__global__ void finalize(const float* __restrict__ dist, const float* __restrict__ QS,
                         const float* __restrict__ gt, const float* __restrict__ tw,
                         float* __restrict__ out)
{
    int i = blockIdx.x * 256 + threadIdx.x;
    if (i < 2500) {
        int q = i / 5, c = i - q * 5;
        out[i] = -(dist[c * 500 + q] + QS[q]) * (gt[0] * tw[0] * (1.f / 28.f));
    }
}

// ---------------------------------------------------------------------------
extern "C" void kernel_launch(void* const* d_in, const int* in_sizes, int n_in,
                              void* d_out, int out_size, void* d_ws, size_t ws_size,
                              hipStream_t stream)
{
    const float* support = (const float*)d_in[0];
    const float* queries = (const float*)d_in[2];
    const float* kw      = (const float*)d_in[3];
    const float* kb      = (const float*)d_in[4];
    const float* vw      = (const float*)d_in[5];
    const float* vb      = (const float*)d_in[6];
    const float* gamma   = (const float*)d_in[7];
    const float* beta    = (const float*)d_in[8];
    const float* gt      = (const float*)d_in[9];
    const float* tw      = (const float*)d_in[10];
    float* out = (float*)d_out;

    char* ws = (char*)d_ws;
    size_t off = 0;
    auto alloc = [&](size_t b) { char* p = ws + off; off += (b + 255) & ~(size_t)255; return p; };
    bf16* X      = (bf16*)alloc(4224ull * 2048 * 2);
    bf16* Wp     = (bf16*)alloc(4608ull * 2048 * 2);
    // union: H [4224x4608 bf16, 38.9MB] first; then attn+attnG [21.6MB each]
    char* uni    = alloc(14080ull * 768 * 4);
    bf16* H      = (bf16*)uni;
    bf16* attn   = (bf16*)uni;
    bf16* attnG  = (bf16*)(uni + 14080ull * 768 * 2);
    // FG: [Fkt(4224); Fkb(4224); Fvt(4224); Fvb(4224)] x 768 bf16
    bf16* FG     = (bf16*)alloc(16896ull * 768 * 2);
    bf16* Bk     = (bf16*)alloc(768ull * 1152 * 2);
    bf16* svs    = (bf16*)alloc(768ull * 1152 * 2);
    bf16* Gb     = (bf16*)alloc(768ull * 768 * 2);
    float* MU    = (float*)alloc(14000ull * 4);
    float* RS    = (float*)alloc(14000ull * 4);
    float* gd    = (float*)alloc(768 * 4);
    float* kbd   = (float*)alloc(768 * 4);
    float* bd2   = (float*)alloc(768 * 4);
    float* bdot  = (float*)alloc(768 * 4);
    float* QS    = (float*)alloc(500 * 4);
    float* dist  = (float*)alloc(5 * 500 * 4);

    hipMemsetAsync(dist, 0, 5 * 500 * 4, stream);
    fill_pack<<<4224 + 9216, 256, 0, stream>>>(queries, support, kw, vw, X, Wp);
    // H[4224][4608] = X x Wp^T  (bf16 out)
    gemm_bt<bf16><<<33 * 36, 256, 0, stream>>>(X, 2048, Wp, 2048, H, 4608, 2048, 1.f, 36);
    support_stats<<<1768, 256, 0, stream>>>(H, kb, vb, gamma, beta, Bk, svs,
                                            gd, kbd, bd2, bdot, MU, RS, QS);
    gemm_frames<<<828, 256, 0, stream>>>(H, Bk, svs, FG, Gb);
    assemble_softmax<<<14080, 320, 0, stream>>>(FG, FG + 4224ull * 768, MU, RS, gd, kbd, bd2, attn);
    // attnG[14080][768] = attn x Gb^T
    gemm_bt<bf16><<<110 * 6, 256, 0, stream>>>(attn, 768, Gb, 768, attnG, 768, 768, 1.f, 6);
    final_dist<<<3500, 256, 0, stream>>>(attn, attnG, FG + 0, bdot, dist);
    finalize<<<10, 256, 0, stream>>>(dist, QS, gt, tw, out);
}

// Round 7
// 399.915 us; speedup vs baseline: 1.3269x; 1.0481x over previous
//
#include <hip/hip_runtime.h>

typedef __bf16 bf16;
typedef __attribute__((ext_vector_type(8))) __bf16 bf16x8;
typedef __attribute__((ext_vector_type(4))) float f32x4;

#define AS1 __attribute__((address_space(1)))
#define AS3 __attribute__((address_space(3)))

// tuple tables: combinations(range(8), 2), lexicographic
__device__ __constant__ int c_T0[28] = {0,0,0,0,0,0,0,1,1,1,1,1,1,2,2,2,2,2,3,3,3,3,4,4,4,5,5,6};
__device__ __constant__ int c_T1[28] = {1,2,3,4,5,6,7,2,3,4,5,6,7,3,4,5,6,7,4,5,6,7,5,6,7,6,7,7};

// ---------------------------------------------------------------------------
// Merged: blocks < 4224 fill X (frames + PE); blocks >= 4224 pack Wp.
__global__ __launch_bounds__(256) void fill_pack(
    const float* __restrict__ queries, const float* __restrict__ support,
    const float* __restrict__ kw, const float* __restrict__ vw,
    bf16* __restrict__ X, bf16* __restrict__ Wp)
{
    __shared__ float t[32][33];
    const int tid = threadIdx.x;
    if (blockIdx.x < 4224) {
        const int f = blockIdx.x;
        bf16* row = X + (long)f * 2048;
        const int d0 = tid << 3;
        if (f >= 4200) {
            bf16x8 z;
            #pragma unroll
            for (int i = 0; i < 8; ++i) z[i] = (bf16)0.f;
            *(bf16x8*)(row + d0) = z;
            return;
        }
        const float* src = (f < 4000) ? (queries + (long)f * 2048)
                                      : (support + (long)(f - 4000) * 2048);
        const int s = f & 7;
        bf16x8 o;
        #pragma unroll
        for (int i = 0; i < 8; ++i) {
            int d = d0 + i;
            float dv = __expf((float)(d >> 1) * -0.008994473019508f); // -ln(1e4)/1024
            float ang = (float)s * dv;
            float pe = (d & 1) ? __cosf(ang) : __sinf(ang);
            o[i] = (bf16)(src[d] + pe);
        }
        *(bf16x8*)(row + d0) = o;
    } else {
        const int b = blockIdx.x - 4224;
        const int k0 = (b & 63) << 5, n0g = (b >> 6) << 5;
        const int tx = tid & 31, ty = tid >> 5;
        const int j = n0g / 1152, nc = n0g % 1152;
        const float* src = ((j < 2) ? kw : vw) + (long)(((j & 1) << 11) + k0) * 1152 + nc;
        #pragma unroll
        for (int i = 0; i < 4; ++i)
            t[ty + (i << 3)][tx] = src[(long)(ty + (i << 3)) * 1152 + tx];
        __syncthreads();
        #pragma unroll
        for (int i = 0; i < 4; ++i)
            Wp[(long)(n0g + ty + (i << 3)) * 2048 + k0 + tx] = (bf16)t[tx][ty + (i << 3)];
    }
}

// ---------------------------------------------------------------------------
// C[M,N] = scale * A[M,K](bf16, lda) x B[N,K](bf16, ldb)^T.  Row-major block
// order (no swizzle — R4 showed swizzle hurts locality here).
template <typename OutT>
__global__ __launch_bounds__(256) void gemm_bt(
    const bf16* __restrict__ A, long lda, const bf16* __restrict__ B, long ldb,
    OutT* __restrict__ C, int N, int K, float scale, int tiles_n)
{
    __shared__ __align__(16) bf16 lA[128 * 32];
    __shared__ __align__(16) bf16 lB[128 * 32];
    const int tid = threadIdx.x;
    const int wid = tid >> 6, lane = tid & 63;
    const int wm = (wid >> 1) << 6, wn = (wid & 1) << 6;
    const int quad = lane >> 4, l16 = lane & 15;
    const int tm = blockIdx.x / tiles_n, tn = blockIdx.x % tiles_n;
    const int m0 = tm << 7, n0 = tn << 7;
    const bf16* Abase = A + (long)m0 * lda;

    f32x4 acc[4][4];
    #pragma unroll
    for (int i = 0; i < 4; ++i)
        #pragma unroll
        for (int j = 0; j < 4; ++j)
            #pragma unroll
            for (int r = 0; r < 4; ++r) acc[i][j][r] = 0.f;

    const int srow = lane >> 2, scol = (lane & 3) << 3;
    for (int kk = 0; kk < K; kk += 32) {
        __syncthreads();
        #pragma unroll
        for (int p = 0; p < 2; ++p) {
            const int rbase = (wid << 5) + (p << 4);
            const bf16* ga = Abase + (long)(rbase + srow) * lda + kk + scol;
            const bf16* gb = B + (long)(n0 + rbase + srow) * ldb + kk + scol;
            __builtin_amdgcn_global_load_lds((const AS1 unsigned int*)ga,
                                             (AS3 unsigned int*)(lA + rbase * 32), 16, 0, 0);
            __builtin_amdgcn_global_load_lds((const AS1 unsigned int*)gb,
                                             (AS3 unsigned int*)(lB + rbase * 32), 16, 0, 0);
        }
        __builtin_amdgcn_s_waitcnt(0);
        __syncthreads();
        bf16x8 af[4], bfr[4];
        #pragma unroll
        for (int i = 0; i < 4; ++i)
            af[i] = *(const bf16x8*)(lA + (wm + (i << 4) + l16) * 32 + (quad << 3));
        #pragma unroll
        for (int j = 0; j < 4; ++j)
            bfr[j] = *(const bf16x8*)(lB + (wn + (j << 4) + l16) * 32 + (quad << 3));
        #pragma unroll
        for (int i = 0; i < 4; ++i)
            #pragma unroll
            for (int j = 0; j < 4; ++j)
                acc[i][j] = __builtin_amdgcn_mfma_f32_16x16x32_bf16(af[i], bfr[j], acc[i][j], 0, 0, 0);
    }
    #pragma unroll
    for (int i = 0; i < 4; ++i) {
        const int row = m0 + wm + (i << 4) + (quad << 2);
        #pragma unroll
        for (int j = 0; j < 4; ++j) {
            const int col = n0 + wn + (j << 4) + l16;
            OutT* cp = C + (long)row * N + col;
            #pragma unroll
            for (int r = 0; r < 4; ++r) cp[(long)r * N] = (OutT)(acc[i][j][r] * scale);
        }
    }
}

// ---------------------------------------------------------------------------
// Per-frame GEMMs in one launch.  828 blocks:
//   bid <  792: seg = bid/198 in {0:Fkt, 1:Fkb, 2:Fvt, 3:Fvb};
//               A = H col-segment seg*1152 (lda 4608), B = (seg<2 ? Bk : svs),
//               C = FG + seg*4224 rows (bf16).
//   bid >= 792: Gram = svs x svs^T -> compact per-class G5[5][144][160] bf16
//               (pads pre-zeroed by memset).
__global__ __launch_bounds__(256) void gemm_frames(
    const bf16* __restrict__ H, const bf16* __restrict__ Bk,
    const bf16* __restrict__ svs, bf16* __restrict__ FG, bf16* __restrict__ G5)
{
    __shared__ __align__(16) bf16 lA[128 * 32];
    __shared__ __align__(16) bf16 lB[128 * 32];
    const int tid = threadIdx.x;
    const int wid = tid >> 6, lane = tid & 63;
    const int wm = (wid >> 1) << 6, wn = (wid & 1) << 6;
    const int quad = lane >> 4, l16 = lane & 15;
    const bool gram = (int)blockIdx.x >= 792;
    int seg = 4, tm, tn;
    const bf16* Abase;
    long la;
    const bf16* B;
    if (!gram) {
        seg = blockIdx.x / 198;
        int r = blockIdx.x % 198;
        tm = r / 6; tn = r % 6;
        Abase = H + seg * 1152 + (long)(tm << 7) * 4608;
        la = 4608;
        B = (seg < 2) ? Bk : svs;
    } else {
        int r = blockIdx.x - 792;
        tm = r / 6; tn = r % 6;
        Abase = svs + (long)(tm << 7) * 1152;
        la = 1152;
        B = svs;
    }
    const int n0 = tn << 7;

    f32x4 acc[4][4];
    #pragma unroll
    for (int i = 0; i < 4; ++i)
        #pragma unroll
        for (int j = 0; j < 4; ++j)
            #pragma unroll
            for (int r = 0; r < 4; ++r) acc[i][j][r] = 0.f;

    const int srow = lane >> 2, scol = (lane & 3) << 3;
    for (int kk = 0; kk < 1152; kk += 32) {
        __syncthreads();
        #pragma unroll
        for (int p = 0; p < 2; ++p) {
            const int rbase = (wid << 5) + (p << 4);
            const bf16* ga = Abase + (long)(rbase + srow) * la + kk + scol;
            const bf16* gb = B + (long)(n0 + rbase + srow) * 1152 + kk + scol;
            __builtin_amdgcn_global_load_lds((const AS1 unsigned int*)ga,
                                             (AS3 unsigned int*)(lA + rbase * 32), 16, 0, 0);
            __builtin_amdgcn_global_load_lds((const AS1 unsigned int*)gb,
                                             (AS3 unsigned int*)(lB + rbase * 32), 16, 0, 0);
        }
        __builtin_amdgcn_s_waitcnt(0);
        __syncthreads();
        bf16x8 af[4], bfr[4];
        #pragma unroll
        for (int i = 0; i < 4; ++i)
            af[i] = *(const bf16x8*)(lA + (wm + (i << 4) + l16) * 32 + (quad << 3));
        #pragma unroll
        for (int j = 0; j < 4; ++j)
            bfr[j] = *(const bf16x8*)(lB + (wn + (j << 4) + l16) * 32 + (quad << 3));
        #pragma unroll
        for (int i = 0; i < 4; ++i)
            #pragma unroll
            for (int j = 0; j < 4; ++j)
                acc[i][j] = __builtin_amdgcn_mfma_f32_16x16x32_bf16(af[i], bfr[j], acc[i][j], 0, 0, 0);
    }
    #pragma unroll
    for (int i = 0; i < 4; ++i) {
        const int rloc = (tm << 7) + wm + (i << 4) + (quad << 2);
        #pragma unroll
        for (int j = 0; j < 4; ++j) {
            const int col = n0 + wn + (j << 4) + l16;
            #pragma unroll
            for (int r = 0; r < 4; ++r) {
                const int row = rloc + r;
                if (!gram) {
                    FG[(long)(seg * 4224 + row) * 768 + col] = (bf16)acc[i][j][r];
                } else {
                    if (row < 700 && col < 700 && row / 140 == col / 140) {
                        int cc = row / 140;
                        G5[((long)cc * 144 + (row - cc * 140)) * 160 + (col - cc * 140)]
                            = (bf16)acc[i][j][r];
                    }
                }
            }
        }
    }
}

// ---------------------------------------------------------------------------
// Merged support projection + per-query stats (shared-mem union).
// Blocks 0..767: support tuple rows -> Bk = gamma.*sks, svs; scalars.
// Blocks 768..1267:  K-side frame dots -> MU[m], RS[m].
// Blocks 1268..1767: V-side frame dots -> QS[q].
__global__ __launch_bounds__(256) void support_stats(
    const bf16* __restrict__ H, const float* __restrict__ kb,
    const float* __restrict__ vb, const float* __restrict__ gamma,
    const float* __restrict__ beta,
    bf16* __restrict__ Bk, bf16* __restrict__ svs,
    float* __restrict__ gd, float* __restrict__ kbd,
    float* __restrict__ bd2, float* __restrict__ bdot,
    float* __restrict__ MU, float* __restrict__ RS, float* __restrict__ QS)
{
    __shared__ __align__(16) char smem[2 * 9216 * 2 + 512];
    const int tid = threadIdx.x;
    const int wid = tid >> 6, lane = tid & 63;
    if ((int)blockIdx.x < 768) {
        const int u = blockIdx.x;
        bf16* outK = Bk + (long)u * 1152;
        bf16* outV = svs + (long)u * 1152;
        if (u >= 700) {
            for (int d = tid; d < 1152; d += 256) { outK[d] = (bf16)0.f; outV[d] = (bf16)0.f; }
            if (tid == 0) { gd[u] = 0.f; kbd[u] = 0.f; bd2[u] = 0.f; bdot[u] = 0.f; }
            return;
        }
        float* s1 = (float*)smem;
        float* s2 = s1 + 4;
        float* sr = s2 + 4;
        const int n = u / 28, t = u - n * 28;
        const int fi = 4000 + (n << 3) + c_T0[t];
        const int fj = 4000 + (n << 3) + c_T1[t];
        const bf16* Hi = H + (long)fi * 4608;
        const bf16* Hj = H + (long)fj * 4608;
        float xv[5];
        float sum = 0.f, sumsq = 0.f;
        #pragma unroll
        for (int it = 0; it < 5; ++it) {
            int d = tid + (it << 8);
            float x = 0.f;
            if (d < 1152) {
                x = (float)Hi[d] + (float)Hj[1152 + d] + kb[d];
                sum += x; sumsq += x * x;
            }
            xv[it] = x;
        }
        #pragma unroll
        for (int off = 32; off > 0; off >>= 1) {
            sum += __shfl_xor(sum, off, 64);
            sumsq += __shfl_xor(sumsq, off, 64);
        }
        if ((tid & 63) == 0) { s1[wid] = sum; s2[wid] = sumsq; }
        __syncthreads();
        sum = s1[0] + s1[1] + s1[2] + s1[3];
        sumsq = s2[0] + s2[1] + s2[2] + s2[3];
        const float mu = sum * (1.f / 1152.f);
        const float var = sumsq * (1.f / 1152.f) - mu * mu;
        const float rs = rsqrtf(var + 1e-5f);
        float g_ = 0.f, k_ = 0.f, b_ = 0.f, v_ = 0.f;
        #pragma unroll
        for (int it = 0; it < 5; ++it) {
            int d = tid + (it << 8);
            if (d < 1152) {
                float gm = gamma[d];
                float sk = (xv[it] - mu) * rs * gm + beta[d];
                outK[d] = (bf16)(gm * sk);
                g_ += gm * sk;
                k_ += kb[d] * gm * sk;
                b_ += beta[d] * sk;
                float sv = (float)Hi[2304 + d] + (float)Hj[3456 + d] + vb[d];
                outV[d] = (bf16)sv;
                v_ += vb[d] * sv;
            }
        }
        #pragma unroll
        for (int off = 32; off > 0; off >>= 1) {
            g_ += __shfl_xor(g_, off, 64);
            k_ += __shfl_xor(k_, off, 64);
            b_ += __shfl_xor(b_, off, 64);
            v_ += __shfl_xor(v_, off, 64);
        }
        if ((tid & 63) == 0) { sr[wid * 4 + 0] = g_; sr[wid * 4 + 1] = k_; sr[wid * 4 + 2] = b_; sr[wid * 4 + 3] = v_; }
        __syncthreads();
        if (tid == 0) {
            gd[u]   = sr[0] + sr[4] + sr[8]  + sr[12];
            kbd[u]  = sr[1] + sr[5] + sr[9]  + sr[13];
            bd2[u]  = sr[2] + sr[6] + sr[10] + sr[14];
            bdot[u] = sr[3] + sr[7] + sr[11] + sr[15];
        }
        return;
    }
    const int s_ = blockIdx.x - 768;
    const bool kside = s_ < 500;
    const int q = kside ? s_ : s_ - 500;
    const int co = kside ? 0 : 2304;
    const float* bias = kside ? kb : vb;
    bf16* Ft = (bf16*)smem;
    bf16* Fb = Ft + 9216;
    float* fl = (float*)(smem + 36864);
    float* Sa = fl;        // [8]
    float* Qa = fl + 8;    // [8]
    float* Ca = fl + 16;   // [8]
    float* Sb_ = fl + 24;  // [8]
    float* Qb_ = fl + 32;  // [8]
    float* Cb_ = fl + 40;  // [8]
    float* Pp = fl + 48;   // [28]
    float* Sk2 = fl + 76;  // [2]
    for (int idx = tid; idx < 1152; idx += 256) {
        int row = idx / 144, col = (idx - row * 144) << 3;
        const bf16* src = H + (long)((q << 3) + row) * 4608 + co;
        *(bf16x8*)(Ft + row * 1152 + col) = *(const bf16x8*)(src + col);
        *(bf16x8*)(Fb + row * 1152 + col) = *(const bf16x8*)(src + 1152 + col);
    }
    __syncthreads();
    for (int task = wid; task < 45; task += 4) {
        float s0 = 0.f, s1v = 0.f, s2v = 0.f;
        if (task < 16) {
            const bf16* p = (task < 8) ? (Ft + task * 1152) : (Fb + (task - 8) * 1152);
            for (int c = lane << 3; c < 1152; c += 512) {
                bf16x8 v = *(const bf16x8*)(p + c);
                #pragma unroll
                for (int k = 0; k < 8; ++k) {
                    float f = (float)v[k];
                    s0 += f; s1v += f * f; s2v += f * bias[c + k];
                }
            }
        } else if (task < 44) {
            int t = task - 16;
            const bf16* pa = Ft + c_T0[t] * 1152;
            const bf16* pb = Fb + c_T1[t] * 1152;
            for (int c = lane << 3; c < 1152; c += 512) {
                bf16x8 a = *(const bf16x8*)(pa + c);
                bf16x8 b = *(const bf16x8*)(pb + c);
                #pragma unroll
                for (int k = 0; k < 8; ++k) s0 += (float)a[k] * (float)b[k];
            }
        } else {
            for (int c = lane << 3; c < 1152; c += 512) {
                #pragma unroll
                for (int k = 0; k < 8; ++k) { float f = bias[c + k]; s0 += f; s1v += f * f; }
            }
        }
        #pragma unroll
        for (int off = 32; off > 0; off >>= 1) {
            s0 += __shfl_xor(s0, off, 64);
            s1v += __shfl_xor(s1v, off, 64);
            s2v += __shfl_xor(s2v, off, 64);
        }
        if (lane == 0) {
            if (task < 8)       { Sa[task] = s0; Qa[task] = s1v; Ca[task] = s2v; }
            else if (task < 16) { Sb_[task - 8] = s0; Qb_[task - 8] = s1v; Cb_[task - 8] = s2v; }
            else if (task < 44) Pp[task - 16] = s0;
            else                { Sk2[0] = s0; Sk2[1] = s1v; }
        }
    }
    __syncthreads();
    if (kside) {
        if (tid < 28) {
            int i = c_T0[tid], j = c_T1[tid];
            float mu = (Sa[i] + Sb_[j] + Sk2[0]) * (1.f / 1152.f);
            float ex2 = (Qa[i] + Qb_[j] + Sk2[1] + 2.f * (Pp[tid] + Ca[i] + Cb_[j])) * (1.f / 1152.f);
            float var = ex2 - mu * mu;
            int m = q * 28 + tid;
            MU[m] = mu;
            RS[m] = rsqrtf(var + 1e-5f);
        }
    } else {
        if (tid < 64) {
            float term = 0.f;
            if (lane < 28) {
                int i = c_T0[lane], j = c_T1[lane];
                term = Qa[i] + Qb_[j] + Sk2[1] + 2.f * (Pp[lane] + Ca[i] + Cb_[j]);
            }
            #pragma unroll
            for (int off = 32; off > 0; off >>= 1) term += __shfl_xor(term, off, 64);
            if (lane == 0) QS[q] = term;
        }
    }
}

// ---------------------------------------------------------------------------
// Assemble scores from per-frame products (bf16) + LN stats, softmax per
// class, write attn5[class][m][144] (pad cols 140..143 = 0; tail rows zero).
__global__ __launch_bounds__(320) void assemble_softmax(
    const bf16* __restrict__ Fkt, const bf16* __restrict__ Fkb,
    const float* __restrict__ MU, const float* __restrict__ RS,
    const float* __restrict__ gd, const float* __restrict__ kbd,
    const float* __restrict__ bd2, bf16* __restrict__ attn5)
{
    const int m = blockIdx.x, tid = threadIdx.x;
    if (m >= 14000) {
        #pragma unroll
        for (int c = 0; c < 5; ++c)
            for (int d = tid; d < 144; d += 320)
                attn5[((long)c * 14080 + m) * 144 + d] = (bf16)0.f;
        return;
    }
    const int q = m / 28, t = m - q * 28;
    const bf16* ft = Fkt + (long)((q << 3) + c_T0[t]) * 768;
    const bf16* fb = Fkb + (long)((q << 3) + c_T1[t]) * 768;
    const float mu = MU[m], rs = RS[m];
    const int w = tid >> 6, lane = tid & 63;
    const int base = w * 140;
    const float sc = 0.029462782549439484f; // 1/sqrt(1152)
    int u0 = base + lane, u1 = base + 64 + lane, u2 = base + 128 + lane;
    float v0 = (rs * ((float)ft[u0] + (float)fb[u0] + kbd[u0] - mu * gd[u0]) + bd2[u0]) * sc;
    float v1 = (rs * ((float)ft[u1] + (float)fb[u1] + kbd[u1] - mu * gd[u1]) + bd2[u1]) * sc;
    float v2 = (lane < 12)
             ? (rs * ((float)ft[u2] + (float)fb[u2] + kbd[u2] - mu * gd[u2]) + bd2[u2]) * sc
             : -1e30f;
    float mx = fmaxf(fmaxf(v0, v1), v2);
    #pragma unroll
    for (int off = 32; off > 0; off >>= 1) mx = fmaxf(mx, __shfl_xor(mx, off, 64));
    float e0 = __expf(v0 - mx), e1 = __expf(v1 - mx);
    float e2 = (lane < 12) ? __expf(v2 - mx) : 0.f;
    float s = e0 + e1 + e2;
    #pragma unroll
    for (int off = 32; off > 0; off >>= 1) s += __shfl_xor(s, off, 64);
    const float inv = 1.f / s;
    bf16* aw = attn5 + ((long)w * 14080 + m) * 144;
    aw[lane] = (bf16)(e0 * inv);
    aw[64 + lane] = (bf16)(e1 * inv);
    if (lane < 12) aw[128 + lane] = (bf16)(e2 * inv);
    else if (lane < 16) aw[128 + lane] = (bf16)0.f; // pad 140..143
}

// ---------------------------------------------------------------------------
// Fused per-class quadratic form + distance: for class c, row-tile of 128:
//   P = A x G5[c]^T (MFMA from LDS), then per row
//   dist[c][q] += sum_col a * (P - 2*(Fvt[fi]+Fvb[fj]+bdot)).
// Grid 5*110; 256 threads (4 waves x 32 rows).
__global__ __launch_bounds__(256) void class_dist(
    const bf16* __restrict__ attn5, const bf16* __restrict__ G5,
    const bf16* __restrict__ FG, const float* __restrict__ bdot,
    float* __restrict__ dist)
{
    __shared__ __align__(16) bf16 lA[128 * 168];
    __shared__ __align__(16) bf16 lG[144 * 168];
    const int tid = threadIdx.x;
    const int c = blockIdx.x / 110, tm = blockIdx.x % 110;
    const long m0 = (long)tm * 128;
    const bf16* Abase = attn5 + ((long)c * 14080 + m0) * 144;
    // stage A: 128 rows x 144 (vec8), pad 144..159 zero
    for (int v = tid; v < 128 * 18; v += 256) {
        int r = v / 18, k = (v - r * 18) << 3;
        *(bf16x8*)(lA + r * 168 + k) = *(const bf16x8*)(Abase + (long)r * 144 + k);
    }
    {
        int r = tid >> 1, k = 144 + ((tid & 1) << 3);
        bf16x8 z;
        #pragma unroll
        for (int i = 0; i < 8; ++i) z[i] = (bf16)0.f;
        *(bf16x8*)(lA + r * 168 + k) = z;
    }
    // stage G: 144 x 160 (vec8)
    const bf16* Gbase = G5 + (long)c * 144 * 160;
    for (int v = tid; v < 144 * 20; v += 256) {
        int r = v / 20, k = (v - r * 20) << 3;
        *(bf16x8*)(lG + r * 168 + k) = *(const bf16x8*)(Gbase + r * 160 + k);
    }
    __syncthreads();
    const int wid = tid >> 6, lane = tid & 63;
    const int quad = lane >> 4, l16 = lane & 15;
    const int wr = wid << 5;
    f32x4 acc[2][9];
    #pragma unroll
    for (int i = 0; i < 2; ++i)
        #pragma unroll
        for (int j = 0; j < 9; ++j)
            #pragma unroll
            for (int r = 0; r < 4; ++r) acc[i][j][r] = 0.f;
    #pragma unroll
    for (int kk = 0; kk < 160; kk += 32) {
        bf16x8 af0 = *(const bf16x8*)(lA + (wr + l16) * 168 + kk + (quad << 3));
        bf16x8 af1 = *(const bf16x8*)(lA + (wr + 16 + l16) * 168 + kk + (quad << 3));
        #pragma unroll
        for (int j = 0; j < 9; ++j) {
            bf16x8 bf_ = *(const bf16x8*)(lG + ((j << 4) + l16) * 168 + kk + (quad << 3));
            acc[0][j] = __builtin_amdgcn_mfma_f32_16x16x32_bf16(af0, bf_, acc[0][j], 0, 0, 0);
            acc[1][j] = __builtin_amdgcn_mfma_f32_16x16x32_bf16(af1, bf_, acc[1][j], 0, 0, 0);
        }
    }
    // epilogue: per row, sum over cols of a*(P - 2W)
    #pragma unroll
    for (int i = 0; i < 2; ++i) {
        #pragma unroll
        for (int r = 0; r < 4; ++r) {
            const int rl = wr + (i << 4) + (quad << 2) + r;
            const long m = m0 + rl;
            if (m >= 14000) continue;
            const int q = (int)(m / 28), t = (int)(m - (long)q * 28);
            const int fi = (q << 3) + c_T0[t], fj = (q << 3) + c_T1[t];
            const bf16* ft = FG + (long)(8448 + fi) * 768 + c * 140;
            const bf16* fb = FG + (long)(12672 + fj) * 768 + c * 140;
            const float* bd = bdot + c * 140;
            float s = 0.f;
            #pragma unroll
            for (int j = 0; j < 9; ++j) {
                const int col = (j << 4) + l16;
                float a = (float)lA[rl * 168 + col];
                float wv = (float)ft[col] + (float)fb[col] + bd[col];
                s += a * (acc[i][j][r] - 2.f * wv);
            }
            #pragma unroll
            for (int off = 1; off < 16; off <<= 1) s += __shfl_xor(s, off, 64);
            if (l16 == 0) atomicAdd(&dist[c * 500 + q], s);
        }
    }
}

// ---------------------------------------------------------------------------
__global__ void finalize(const float* __restrict__ dist, const float* __restrict__ QS,
                         const float* __restrict__ gt, const float* __restrict__ tw,
                         float* __restrict__ out)
{
    int i = blockIdx.x * 256 + threadIdx.x;
    if (i < 2500) {
        int q = i / 5, c = i - q * 5;
        out[i] = -(dist[c * 500 + q] + QS[q]) * (gt[0] * tw[0] * (1.f / 28.f));
    }
}

// ---------------------------------------------------------------------------
extern "C" void kernel_launch(void* const* d_in, const int* in_sizes, int n_in,
                              void* d_out, int out_size, void* d_ws, size_t ws_size,
                              hipStream_t stream)
{
    const float* support = (const float*)d_in[0];
    const float* queries = (const float*)d_in[2];
    const float* kw      = (const float*)d_in[3];
    const float* kb      = (const float*)d_in[4];
    const float* vw      = (const float*)d_in[5];
    const float* vb      = (const float*)d_in[6];
    const float* gamma   = (const float*)d_in[7];
    const float* beta    = (const float*)d_in[8];
    const float* gt      = (const float*)d_in[9];
    const float* tw      = (const float*)d_in[10];
    float* out = (float*)d_out;

    char* ws = (char*)d_ws;
    size_t off = 0;
    auto alloc = [&](size_t b) { char* p = ws + off; off += (b + 255) & ~(size_t)255; return p; };
    bf16* X      = (bf16*)alloc(4224ull * 2048 * 2);
    bf16* Wp     = (bf16*)alloc(4608ull * 2048 * 2);
    bf16* H      = (bf16*)alloc(4224ull * 4608 * 2);
    // FG: [Fkt(4224); Fkb(4224); Fvt(4224); Fvb(4224)] x 768 bf16
    bf16* FG     = (bf16*)alloc(16896ull * 768 * 2);
    bf16* attn5  = (bf16*)alloc(5ull * 14080 * 144 * 2);
    bf16* Bk     = (bf16*)alloc(768ull * 1152 * 2);
    bf16* svs    = (bf16*)alloc(768ull * 1152 * 2);
    bf16* G5     = (bf16*)alloc(5ull * 144 * 160 * 2);   // 230400 B (multiple of 256)
    float* dist  = (float*)alloc(5 * 500 * 4);           // adjacent to G5
    float* MU    = (float*)alloc(14000ull * 4);
    float* RS    = (float*)alloc(14000ull * 4);
    float* gd    = (float*)alloc(768 * 4);
    float* kbd   = (float*)alloc(768 * 4);
    float* bd2   = (float*)alloc(768 * 4);
    float* bdot  = (float*)alloc(768 * 4);
    float* QS    = (float*)alloc(500 * 4);

    // one memset covers G5 (pad zeros) + dist (accumulator init)
    hipMemsetAsync(G5, 0, 5ull * 144 * 160 * 2 + 5 * 500 * 4, stream);
    fill_pack<<<4224 + 9216, 256, 0, stream>>>(queries, support, kw, vw, X, Wp);
    // H[4224][4608] = X x Wp^T  (bf16 out)
    gemm_bt<bf16><<<33 * 36, 256, 0, stream>>>(X, 2048, Wp, 2048, H, 4608, 2048, 1.f, 36);
    support_stats<<<1768, 256, 0, stream>>>(H, kb, vb, gamma, beta, Bk, svs,
                                            gd, kbd, bd2, bdot, MU, RS, QS);
    gemm_frames<<<828, 256, 0, stream>>>(H, Bk, svs, FG, G5);
    assemble_softmax<<<14080, 320, 0, stream>>>(FG, FG + 4224ull * 768, MU, RS, gd, kbd, bd2, attn5);
    class_dist<<<550, 256, 0, stream>>>(attn5, G5, FG, bdot, dist);
    finalize<<<10, 256, 0, stream>>>(dist, QS, gt, tw, out);
}